// Round 2
// baseline (3373.863 us; speedup 1.0000x reference)
//
#include <hip/hip_runtime.h>

#define DM    128
#define DI    256
#define NH    8
#define HD    32
#define NS    64
#define CDIM  384
#define DPROJ 648
#define LSEQ  4096
#define NB    8
#define NTOK  32768          // NB*LSEQ
#define EPSF  1e-5f

// ---------------- 1. input RMSNorm: xn = rmsnorm(x)*w ----------------
__global__ __launch_bounds__(256) void k_rmsnorm(const float* __restrict__ x,
                                                 const float* __restrict__ w,
                                                 float* __restrict__ xn) {
    int gid = blockIdx.x * 256 + threadIdx.x;
    int row = gid >> 6, lane = gid & 63;
    const float* xr = x + (size_t)row * DM + lane * 2;
    float v0 = xr[0], v1 = xr[1];
    float ss = v0 * v0 + v1 * v1;
    #pragma unroll
    for (int o = 32; o; o >>= 1) ss += __shfl_xor(ss, o);
    float r = rsqrtf(ss * (1.0f / DM) + EPSF);
    float* o = xn + (size_t)row * DM + lane * 2;
    o[0] = v0 * r * w[lane * 2];
    o[1] = v1 * r * w[lane * 2 + 1];
}

// ---------------- 2. GEMM1: zx[M,648] = xn[M,128] @ W1[648,128]^T -------
__global__ __launch_bounds__(256) void k_gemm1(const float* __restrict__ A,
                                               const float* __restrict__ W,
                                               float* __restrict__ C) {
    __shared__ float As[64][68];
    __shared__ float Bs[64][68];
    const int t = threadIdx.x;
    const int m0 = blockIdx.x * 64, n0 = blockIdx.y * 64;
    const int tm = t >> 4, tn = t & 15;
    float acc[4][4] = {};
    for (int k0 = 0; k0 < DM; k0 += 64) {
        __syncthreads();
        #pragma unroll
        for (int i = 0; i < 4; i++) {
            int f4 = t + i * 256;
            int m = f4 >> 4, k4 = f4 & 15;
            *(float4*)&As[m][k4 * 4] = *(const float4*)(A + (size_t)(m0 + m) * DM + k0 + k4 * 4);
            int gn = n0 + m;
            float4 bv = {0.f, 0.f, 0.f, 0.f};
            if (gn < DPROJ) bv = *(const float4*)(W + (size_t)gn * DM + k0 + k4 * 4);
            *(float4*)&Bs[m][k4 * 4] = bv;
        }
        __syncthreads();
        #pragma unroll
        for (int k = 0; k < 64; k += 4) {
            float4 a[4], b[4];
            #pragma unroll
            for (int i = 0; i < 4; i++) a[i] = *(const float4*)&As[tm * 4 + i][k];
            #pragma unroll
            for (int i = 0; i < 4; i++) b[i] = *(const float4*)&Bs[tn * 4 + i][k];
            #pragma unroll
            for (int i = 0; i < 4; i++)
                #pragma unroll
                for (int j = 0; j < 4; j++) {
                    acc[i][j] = fmaf(a[i].x, b[j].x, acc[i][j]);
                    acc[i][j] = fmaf(a[i].y, b[j].y, acc[i][j]);
                    acc[i][j] = fmaf(a[i].z, b[j].z, acc[i][j]);
                    acc[i][j] = fmaf(a[i].w, b[j].w, acc[i][j]);
                }
        }
    }
    #pragma unroll
    for (int i = 0; i < 4; i++) {
        int gm = m0 + tm * 4 + i;
        #pragma unroll
        for (int j = 0; j < 4; j++) {
            int gn = n0 + tn * 4 + j;
            if (gn < DPROJ) C[(size_t)gm * DPROJ + gn] = acc[i][j];
        }
    }
}

// ---------------- 3. causal depthwise conv (K=4) + SiLU ------------------------
__global__ __launch_bounds__(256) void k_conv(const float* __restrict__ zx,
                                              const float* __restrict__ cw,
                                              const float* __restrict__ cb,
                                              float* __restrict__ xc) {
    int gid = blockIdx.x * 256 + threadIdx.x;
    int c = gid % CDIM;
    int r = gid / CDIM;
    int l = r & (LSEQ - 1);
    float4 wv = *(const float4*)(cw + c * 4);
    float acc = cb[c];
    const float* col = zx + (size_t)r * DPROJ + DI + c;
    acc = fmaf(col[0], wv.w, acc);                           // tap l-0
    if (l >= 1) acc = fmaf(col[-1 * DPROJ], wv.z, acc);      // tap l-1
    if (l >= 2) acc = fmaf(col[-2 * DPROJ], wv.y, acc);      // tap l-2
    if (l >= 3) acc = fmaf(col[-3 * DPROJ], wv.x, acc);      // tap l-3
    xc[gid] = acc / (1.f + expf(-acc));                      // silu
}

// ---------------- 4. dt prep: store (softplus(dt+bias), exp(dt*A)) -------------
__global__ __launch_bounds__(256) void k_dt(const float* __restrict__ zx,
                                            const float* __restrict__ dtb,
                                            const float* __restrict__ alog,
                                            float2* __restrict__ dtp) {
    int gid = blockIdx.x * 256 + threadIdx.x;
    int h = gid & 7;
    int r = gid >> 3;
    float v = zx[(size_t)r * DPROJ + 640 + h] + dtb[h];
    float dt = (v > 20.f) ? v : log1pf(expf(v));
    float A = -expf(alog[h]);
    float2 o; o.x = dt; o.y = expf(dt * A);
    dtp[gid] = o;
}

// ---------------- 5. SSM sequential scan ---------------------------------------
// block = (b,h); thread t: p = t>>3 (0..31), j = t&7 -> n = 8j..8j+7 (8 states)
__global__ __launch_bounds__(256) void k_ssm(const float* __restrict__ xc,
                                             const float2* __restrict__ dtp,
                                             const float* __restrict__ Dw,
                                             float* __restrict__ yb) {
    const int b = blockIdx.x >> 3, h = blockIdx.x & 7;
    const int t = threadIdx.x;
    const int p = t >> 3, j = t & 7;
    const float Dh = Dw[h];
    const float* row = xc + (size_t)b * LSEQ * CDIM;
    const float2* dtr = dtp + (size_t)b * LSEQ * NH + h;
    const int xo = h * HD + p, bo = 256 + j * 8, co = 320 + j * 8;
    float hs[8] = {0.f, 0.f, 0.f, 0.f, 0.f, 0.f, 0.f, 0.f};
    float4 B0[2], B1[2], C0[2], C1[2];
    float xv[2]; float2 dtv[2];
    #pragma unroll
    for (int s = 0; s < 2; s++) {
        const float* rp = row + (size_t)s * CDIM;
        B0[s] = *(const float4*)(rp + bo); B1[s] = *(const float4*)(rp + bo + 4);
        C0[s] = *(const float4*)(rp + co); C1[s] = *(const float4*)(rp + co + 4);
        xv[s] = rp[xo]; dtv[s] = dtr[(size_t)s * NH];
    }
    float* yrow = yb + (size_t)b * LSEQ * DI + h * HD + p;
    for (int l = 0; l < LSEQ; l++) {
        const int s = l & 1;
        float4 cB0 = B0[s], cB1 = B1[s], cC0 = C0[s], cC1 = C1[s];
        float cx = xv[s]; float2 cdt = dtv[s];
        int lp = (l + 2 < LSEQ) ? l + 2 : LSEQ - 1;          // depth-2 prefetch
        const float* rp = row + (size_t)lp * CDIM;
        B0[s] = *(const float4*)(rp + bo); B1[s] = *(const float4*)(rp + bo + 4);
        C0[s] = *(const float4*)(rp + co); C1[s] = *(const float4*)(rp + co + 4);
        xv[s] = rp[xo]; dtv[s] = dtr[(size_t)lp * NH];
        const float dA = cdt.y, cf = cdt.x * cx;
        hs[0] = fmaf(hs[0], dA, cf * cB0.x);
        hs[1] = fmaf(hs[1], dA, cf * cB0.y);
        hs[2] = fmaf(hs[2], dA, cf * cB0.z);
        hs[3] = fmaf(hs[3], dA, cf * cB0.w);
        hs[4] = fmaf(hs[4], dA, cf * cB1.x);
        hs[5] = fmaf(hs[5], dA, cf * cB1.y);
        hs[6] = fmaf(hs[6], dA, cf * cB1.z);
        hs[7] = fmaf(hs[7], dA, cf * cB1.w);
        float y0 = hs[0] * cC0.x; y0 = fmaf(hs[1], cC0.y, y0);
        y0 = fmaf(hs[2], cC0.z, y0); y0 = fmaf(hs[3], cC0.w, y0);
        float y1 = hs[4] * cC1.x; y1 = fmaf(hs[5], cC1.y, y1);
        y1 = fmaf(hs[6], cC1.z, y1); y1 = fmaf(hs[7], cC1.w, y1);
        float yp = y0 + y1;
        yp += __shfl_xor(yp, 1);
        yp += __shfl_xor(yp, 2);
        yp += __shfl_xor(yp, 4);
        if (j == 0) yrow[(size_t)l * DI] = fmaf(Dh, cx, yp);
    }
}

// ---------------- 6. gated RMSNorm: y = rmsnorm(y*silu(z))*gw (in-place) -------
__global__ __launch_bounds__(256) void k_gate(float* __restrict__ yb,
                                              const float* __restrict__ zx,
                                              const float* __restrict__ gw) {
    int gid = blockIdx.x * 256 + threadIdx.x;
    int row = gid >> 6, lane = gid & 63;
    float* yr = yb + (size_t)row * DI + lane * 4;
    const float* zr = zx + (size_t)row * DPROJ + lane * 4;
    float4 y = *(const float4*)yr;
    float4 z = *(const float4*)zr;
    float4 g;
    g.x = y.x * (z.x / (1.f + expf(-z.x)));
    g.y = y.y * (z.y / (1.f + expf(-z.y)));
    g.z = y.z * (z.z / (1.f + expf(-z.z)));
    g.w = y.w * (z.w / (1.f + expf(-z.w)));
    float ss = g.x * g.x + g.y * g.y + g.z * g.z + g.w * g.w;
    #pragma unroll
    for (int o = 32; o; o >>= 1) ss += __shfl_xor(ss, o);
    float r = rsqrtf(ss * (1.0f / DI) + EPSF);
    const float4 w = *(const float4*)(gw + lane * 4);
    float4 o;
    o.x = g.x * r * w.x;
    o.y = g.y * r * w.y;
    o.z = g.z * r * w.z;
    o.w = g.w * r * w.w;
    *(float4*)yr = o;
}

// ---------------- 7. GEMM2 + residual: out = x + yn @ W2^T ---------------------
__global__ __launch_bounds__(256) void k_gemm2(const float* __restrict__ A,
                                               const float* __restrict__ W,
                                               const float* __restrict__ xin,
                                               float* __restrict__ out) {
    __shared__ float As[64][68];
    __shared__ float Bs[64][68];
    const int t = threadIdx.x;
    const int m0 = blockIdx.x * 64, n0 = blockIdx.y * 64;
    const int tm = t >> 4, tn = t & 15;
    float acc[4][4] = {};
    for (int k0 = 0; k0 < DI; k0 += 64) {
        __syncthreads();
        #pragma unroll
        for (int i = 0; i < 4; i++) {
            int f4 = t + i * 256;
            int m = f4 >> 4, k4 = f4 & 15;
            *(float4*)&As[m][k4 * 4] = *(const float4*)(A + (size_t)(m0 + m) * DI + k0 + k4 * 4);
            *(float4*)&Bs[m][k4 * 4] = *(const float4*)(W + (size_t)(n0 + m) * DI + k0 + k4 * 4);
        }
        __syncthreads();
        #pragma unroll
        for (int k = 0; k < 64; k += 4) {
            float4 a[4], b[4];
            #pragma unroll
            for (int i = 0; i < 4; i++) a[i] = *(const float4*)&As[tm * 4 + i][k];
            #pragma unroll
            for (int i = 0; i < 4; i++) b[i] = *(const float4*)&Bs[tn * 4 + i][k];
            #pragma unroll
            for (int i = 0; i < 4; i++)
                #pragma unroll
                for (int j = 0; j < 4; j++) {
                    acc[i][j] = fmaf(a[i].x, b[j].x, acc[i][j]);
                    acc[i][j] = fmaf(a[i].y, b[j].y, acc[i][j]);
                    acc[i][j] = fmaf(a[i].z, b[j].z, acc[i][j]);
                    acc[i][j] = fmaf(a[i].w, b[j].w, acc[i][j]);
                }
        }
    }
    #pragma unroll
    for (int i = 0; i < 4; i++) {
        int gm = m0 + tm * 4 + i;
        float4 xv = *(const float4*)(xin + (size_t)gm * DM + n0 + tn * 4);
        float4 o;
        o.x = xv.x + acc[i][0];
        o.y = xv.y + acc[i][1];
        o.z = xv.z + acc[i][2];
        o.w = xv.w + acc[i][3];
        *(float4*)(out + (size_t)gm * DM + n0 + tn * 4) = o;
    }
}

extern "C" void kernel_launch(void* const* d_in, const int* in_sizes, int n_in,
                              void* d_out, int out_size, void* d_ws, size_t ws_size,
                              hipStream_t stream) {
    const float* x   = (const float*)d_in[0];
    const float* nw  = (const float*)d_in[1];
    const float* w1  = (const float*)d_in[2];
    const float* cw  = (const float*)d_in[3];
    const float* cb  = (const float*)d_in[4];
    const float* dtb = (const float*)d_in[5];
    const float* al  = (const float*)d_in[6];
    const float* Dw  = (const float*)d_in[7];
    const float* gw  = (const float*)d_in[8];
    const float* w2  = (const float*)d_in[9];
    float* out = (float*)d_out;

    float* ws = (float*)d_ws;
    float*  zx  = ws;                                   // 32768*648
    float*  xc  = zx + (size_t)NTOK * DPROJ;            // 32768*384
    float2* dtp = (float2*)(xc + (size_t)NTOK * CDIM);  // 32768*8 float2
    float*  yb  = (float*)(dtp + (size_t)NTOK * NH);    // 32768*256
    float*  xn  = yb;                                   // alias: xn dead before yb live

    k_rmsnorm<<<NTOK / 4, 256, 0, stream>>>(x, nw, xn);
    k_gemm1<<<dim3(NTOK / 64, (DPROJ + 63) / 64), 256, 0, stream>>>(xn, w1, zx);
    k_conv<<<(NTOK * CDIM) / 256, 256, 0, stream>>>(zx, cw, cb, xc);
    k_dt<<<(NTOK * NH) / 256, 256, 0, stream>>>(zx, dtb, al, dtp);
    k_ssm<<<NB * NH, 256, 0, stream>>>(xc, dtp, Dw, yb);
    k_gate<<<NTOK / 4, 256, 0, stream>>>(yb, zx, gw);
    k_gemm2<<<dim3(NTOK / 64, DM / 64), 256, 0, stream>>>(yb, w2, x, out);
}

// Round 3
// 759.869 us; speedup vs baseline: 4.4401x; 4.4401x over previous
//
#include <hip/hip_runtime.h>

#define DM    128
#define DI    256
#define NH    8
#define HD    32
#define NS    64
#define CDIM  384
#define DPROJ 648
#define LSEQ  4096
#define NB    8
#define NTOK  32768          // NB*LSEQ
#define LC    64             // chunk length
#define NC    64             // chunks per (b,h) sequence
#define EPSF  1e-5f

// ---------------- 1. input RMSNorm: xn = rmsnorm(x)*w ----------------
__global__ __launch_bounds__(256) void k_rmsnorm(const float* __restrict__ x,
                                                 const float* __restrict__ w,
                                                 float* __restrict__ xn) {
    int gid = blockIdx.x * 256 + threadIdx.x;
    int row = gid >> 6, lane = gid & 63;
    const float* xr = x + (size_t)row * DM + lane * 2;
    float v0 = xr[0], v1 = xr[1];
    float ss = v0 * v0 + v1 * v1;
    #pragma unroll
    for (int o = 32; o; o >>= 1) ss += __shfl_xor(ss, o);
    float r = rsqrtf(ss * (1.0f / DM) + EPSF);
    float* o = xn + (size_t)row * DM + lane * 2;
    o[0] = v0 * r * w[lane * 2];
    o[1] = v1 * r * w[lane * 2 + 1];
}

// ---------------- 2. GEMM1: zx[M,648] = xn[M,128] @ W1[648,128]^T -------
__global__ __launch_bounds__(256) void k_gemm1(const float* __restrict__ A,
                                               const float* __restrict__ W,
                                               float* __restrict__ C) {
    __shared__ float As[64][68];
    __shared__ float Bs[64][68];
    const int t = threadIdx.x;
    const int m0 = blockIdx.x * 64, n0 = blockIdx.y * 64;
    const int tm = t >> 4, tn = t & 15;
    float acc[4][4] = {};
    for (int k0 = 0; k0 < DM; k0 += 64) {
        __syncthreads();
        #pragma unroll
        for (int i = 0; i < 4; i++) {
            int f4 = t + i * 256;
            int m = f4 >> 4, k4 = f4 & 15;
            *(float4*)&As[m][k4 * 4] = *(const float4*)(A + (size_t)(m0 + m) * DM + k0 + k4 * 4);
            int gn = n0 + m;
            float4 bv = {0.f, 0.f, 0.f, 0.f};
            if (gn < DPROJ) bv = *(const float4*)(W + (size_t)gn * DM + k0 + k4 * 4);
            *(float4*)&Bs[m][k4 * 4] = bv;
        }
        __syncthreads();
        #pragma unroll
        for (int k = 0; k < 64; k += 4) {
            float4 a[4], b[4];
            #pragma unroll
            for (int i = 0; i < 4; i++) a[i] = *(const float4*)&As[tm * 4 + i][k];
            #pragma unroll
            for (int i = 0; i < 4; i++) b[i] = *(const float4*)&Bs[tn * 4 + i][k];
            #pragma unroll
            for (int i = 0; i < 4; i++)
                #pragma unroll
                for (int j = 0; j < 4; j++) {
                    acc[i][j] = fmaf(a[i].x, b[j].x, acc[i][j]);
                    acc[i][j] = fmaf(a[i].y, b[j].y, acc[i][j]);
                    acc[i][j] = fmaf(a[i].z, b[j].z, acc[i][j]);
                    acc[i][j] = fmaf(a[i].w, b[j].w, acc[i][j]);
                }
        }
    }
    #pragma unroll
    for (int i = 0; i < 4; i++) {
        int gm = m0 + tm * 4 + i;
        #pragma unroll
        for (int j = 0; j < 4; j++) {
            int gn = n0 + tn * 4 + j;
            if (gn < DPROJ) C[(size_t)gm * DPROJ + gn] = acc[i][j];
        }
    }
}

// ---------------- 3. causal depthwise conv (K=4) + SiLU ------------------------
__global__ __launch_bounds__(256) void k_conv(const float* __restrict__ zx,
                                              const float* __restrict__ cw,
                                              const float* __restrict__ cb,
                                              float* __restrict__ xc) {
    int gid = blockIdx.x * 256 + threadIdx.x;
    int c = gid % CDIM;
    int r = gid / CDIM;
    int l = r & (LSEQ - 1);
    float4 wv = *(const float4*)(cw + c * 4);
    float acc = cb[c];
    const float* col = zx + (size_t)r * DPROJ + DI + c;
    acc = fmaf(col[0], wv.w, acc);                           // tap l-0
    if (l >= 1) acc = fmaf(col[-1 * DPROJ], wv.z, acc);      // tap l-1
    if (l >= 2) acc = fmaf(col[-2 * DPROJ], wv.y, acc);      // tap l-2
    if (l >= 3) acc = fmaf(col[-3 * DPROJ], wv.x, acc);      // tap l-3
    xc[gid] = acc / (1.f + expf(-acc));                      // silu
}

// ---------------- 4. dt prep: store (softplus(dt+bias), exp(dt*A)) -------------
__global__ __launch_bounds__(256) void k_dt(const float* __restrict__ zx,
                                            const float* __restrict__ dtb,
                                            const float* __restrict__ alog,
                                            float2* __restrict__ dtp) {
    int gid = blockIdx.x * 256 + threadIdx.x;
    int h = gid & 7;
    int r = gid >> 3;
    float v = zx[(size_t)r * DPROJ + 640 + h] + dtb[h];
    float dt = (v > 20.f) ? v : log1pf(expf(v));
    float A = -expf(alog[h]);
    float2 o; o.x = dt; o.y = expf(dt * A);
    dtp[gid] = o;
}

// ---------------- 5a. SSM pass 1: per-chunk local end-state + decay product ----
// block = (b,h,cgroup of 4); wave w -> chunk cg*4+w. lane: pg=lane>>3 (4 p's),
// j=lane&7 (8 n's). h-tile: 4x8 = 32 regs/lane.
__global__ __launch_bounds__(256) void k_ssm1(const float* __restrict__ xc,
                                              const float2* __restrict__ dtp,
                                              float* __restrict__ hst,
                                              float* __restrict__ dAp) {
    const int bh = blockIdx.x >> 4, cg = blockIdx.x & 15;
    const int b = bh >> 3, h = bh & 7;
    const int wave = threadIdx.x >> 6, lane = threadIdx.x & 63;
    const int c = cg * 4 + wave;
    const int l0 = c * LC;
    const int pg = lane >> 3, j = lane & 7;
    const int pb = pg * 4;
    const int bo = 256 + j * 8, xo = h * HD + pb;
    const float* row = xc + ((size_t)b * LSEQ + l0) * CDIM;
    const float2* dtr = dtp + ((size_t)b * LSEQ + l0) * NH + h;
    float hs[4][8] = {};
    float4 Bv[2][2]; float4 xv[2]; float2 dtv[2];
    #pragma unroll
    for (int s = 0; s < 2; s++) {
        const float* rp = row + s * CDIM;
        Bv[s][0] = *(const float4*)(rp + bo);
        Bv[s][1] = *(const float4*)(rp + bo + 4);
        xv[s] = *(const float4*)(rp + xo);
        dtv[s] = dtr[s * NH];
    }
    float dAprod = 1.f;
    for (int t = 0; t < LC; t++) {
        const int s = t & 1;
        float4 cB0 = Bv[s][0], cB1 = Bv[s][1], cx = xv[s]; float2 cdt = dtv[s];
        int lp = (t + 2 < LC) ? t + 2 : LC - 1;
        const float* rp = row + lp * CDIM;
        Bv[s][0] = *(const float4*)(rp + bo);
        Bv[s][1] = *(const float4*)(rp + bo + 4);
        xv[s] = *(const float4*)(rp + xo);
        dtv[s] = dtr[lp * NH];
        const float dA = cdt.y;
        dAprod *= dA;
        const float cf0 = cdt.x * cx.x, cf1 = cdt.x * cx.y;
        const float cf2 = cdt.x * cx.z, cf3 = cdt.x * cx.w;
        const float Bk[8] = {cB0.x, cB0.y, cB0.z, cB0.w, cB1.x, cB1.y, cB1.z, cB1.w};
        #pragma unroll
        for (int k = 0; k < 8; k++) {
            hs[0][k] = fmaf(hs[0][k], dA, cf0 * Bk[k]);
            hs[1][k] = fmaf(hs[1][k], dA, cf1 * Bk[k]);
            hs[2][k] = fmaf(hs[2][k], dA, cf2 * Bk[k]);
            hs[3][k] = fmaf(hs[3][k], dA, cf3 * Bk[k]);
        }
    }
    float* base = hst + (((size_t)bh * NC + c) << 11);
    #pragma unroll
    for (int i = 0; i < 4; i++) {
        float4 v0 = {hs[i][0], hs[i][1], hs[i][2], hs[i][3]};
        float4 v1 = {hs[i][4], hs[i][5], hs[i][6], hs[i][7]};
        *(float4*)(base + (pb + i) * 64 + j * 8) = v0;
        *(float4*)(base + (pb + i) * 64 + j * 8 + 4) = v1;
    }
    if (lane == 0) dAp[(size_t)bh * NC + c] = dAprod;
}

// ---------------- 5b. SSM pass 2: exclusive scan over chunk states (in place) --
// block = (bh, seg); thread handles state element s = seg*256+t. 64 seq steps.
__global__ __launch_bounds__(256) void k_ssm2(float* __restrict__ hst,
                                              const float* __restrict__ dAp) {
    const int bh = blockIdx.x >> 3, seg = blockIdx.x & 7;
    const int s = seg * 256 + threadIdx.x;
    float* base = hst + ((size_t)bh * NC << 11) + s;
    const float* dap = dAp + (size_t)bh * NC;
    float run = 0.f;
    for (int c = 0; c < NC; c++) {
        float tmp = base[(size_t)c << 11];
        base[(size_t)c << 11] = run;
        run = fmaf(run, dap[c], tmp);
    }
}

// ---------------- 5c. SSM pass 3: re-scan chunk with incoming state, emit y ----
__global__ __launch_bounds__(256) void k_ssm3(const float* __restrict__ xc,
                                              const float2* __restrict__ dtp,
                                              const float* __restrict__ hst,
                                              const float* __restrict__ Dw,
                                              float* __restrict__ yb) {
    const int bh = blockIdx.x >> 4, cg = blockIdx.x & 15;
    const int b = bh >> 3, h = bh & 7;
    const int wave = threadIdx.x >> 6, lane = threadIdx.x & 63;
    const int c = cg * 4 + wave;
    const int l0 = c * LC;
    const int pg = lane >> 3, j = lane & 7;
    const int pb = pg * 4;
    const int bo = 256 + j * 8, co = 320 + j * 8, xo = h * HD + pb;
    const float Dh = Dw[h];
    const float* row = xc + ((size_t)b * LSEQ + l0) * CDIM;
    const float2* dtr = dtp + ((size_t)b * LSEQ + l0) * NH + h;
    // load incoming state
    float hs[4][8];
    const float* hbase = hst + (((size_t)bh * NC + c) << 11);
    #pragma unroll
    for (int i = 0; i < 4; i++) {
        float4 v0 = *(const float4*)(hbase + (pb + i) * 64 + j * 8);
        float4 v1 = *(const float4*)(hbase + (pb + i) * 64 + j * 8 + 4);
        hs[i][0] = v0.x; hs[i][1] = v0.y; hs[i][2] = v0.z; hs[i][3] = v0.w;
        hs[i][4] = v1.x; hs[i][5] = v1.y; hs[i][6] = v1.z; hs[i][7] = v1.w;
    }
    float4 Bv[2][2], Cv[2][2]; float4 xv[2]; float2 dtv[2];
    #pragma unroll
    for (int s = 0; s < 2; s++) {
        const float* rp = row + s * CDIM;
        Bv[s][0] = *(const float4*)(rp + bo);
        Bv[s][1] = *(const float4*)(rp + bo + 4);
        Cv[s][0] = *(const float4*)(rp + co);
        Cv[s][1] = *(const float4*)(rp + co + 4);
        xv[s] = *(const float4*)(rp + xo);
        dtv[s] = dtr[s * NH];
    }
    float* yrow = yb + ((size_t)b * LSEQ + l0) * DI + h * HD + pb;
    for (int t = 0; t < LC; t++) {
        const int s = t & 1;
        float4 cB0 = Bv[s][0], cB1 = Bv[s][1];
        float4 cC0 = Cv[s][0], cC1 = Cv[s][1];
        float4 cx = xv[s]; float2 cdt = dtv[s];
        int lp = (t + 2 < LC) ? t + 2 : LC - 1;
        const float* rp = row + lp * CDIM;
        Bv[s][0] = *(const float4*)(rp + bo);
        Bv[s][1] = *(const float4*)(rp + bo + 4);
        Cv[s][0] = *(const float4*)(rp + co);
        Cv[s][1] = *(const float4*)(rp + co + 4);
        xv[s] = *(const float4*)(rp + xo);
        dtv[s] = dtr[lp * NH];
        const float dA = cdt.y;
        const float cf0 = cdt.x * cx.x, cf1 = cdt.x * cx.y;
        const float cf2 = cdt.x * cx.z, cf3 = cdt.x * cx.w;
        const float Bk[8] = {cB0.x, cB0.y, cB0.z, cB0.w, cB1.x, cB1.y, cB1.z, cB1.w};
        const float Ck[8] = {cC0.x, cC0.y, cC0.z, cC0.w, cC1.x, cC1.y, cC1.z, cC1.w};
        float y0 = 0.f, y1 = 0.f, y2 = 0.f, y3 = 0.f;
        #pragma unroll
        for (int k = 0; k < 8; k++) {
            hs[0][k] = fmaf(hs[0][k], dA, cf0 * Bk[k]);
            hs[1][k] = fmaf(hs[1][k], dA, cf1 * Bk[k]);
            hs[2][k] = fmaf(hs[2][k], dA, cf2 * Bk[k]);
            hs[3][k] = fmaf(hs[3][k], dA, cf3 * Bk[k]);
            y0 = fmaf(hs[0][k], Ck[k], y0);
            y1 = fmaf(hs[1][k], Ck[k], y1);
            y2 = fmaf(hs[2][k], Ck[k], y2);
            y3 = fmaf(hs[3][k], Ck[k], y3);
        }
        #pragma unroll
        for (int o = 1; o <= 4; o <<= 1) {
            y0 += __shfl_xor(y0, o);
            y1 += __shfl_xor(y1, o);
            y2 += __shfl_xor(y2, o);
            y3 += __shfl_xor(y3, o);
        }
        if (j == 0) {
            float4 yo;
            yo.x = fmaf(Dh, cx.x, y0);
            yo.y = fmaf(Dh, cx.y, y1);
            yo.z = fmaf(Dh, cx.z, y2);
            yo.w = fmaf(Dh, cx.w, y3);
            *(float4*)(yrow + (size_t)t * DI) = yo;
        }
    }
}

// ---------------- 6. gated RMSNorm: y = rmsnorm(y*silu(z))*gw (in-place) -------
__global__ __launch_bounds__(256) void k_gate(float* __restrict__ yb,
                                              const float* __restrict__ zx,
                                              const float* __restrict__ gw) {
    int gid = blockIdx.x * 256 + threadIdx.x;
    int row = gid >> 6, lane = gid & 63;
    float* yr = yb + (size_t)row * DI + lane * 4;
    const float* zr = zx + (size_t)row * DPROJ + lane * 4;
    float4 y = *(const float4*)yr;
    float4 z = *(const float4*)zr;
    float4 g;
    g.x = y.x * (z.x / (1.f + expf(-z.x)));
    g.y = y.y * (z.y / (1.f + expf(-z.y)));
    g.z = y.z * (z.z / (1.f + expf(-z.z)));
    g.w = y.w * (z.w / (1.f + expf(-z.w)));
    float ss = g.x * g.x + g.y * g.y + g.z * g.z + g.w * g.w;
    #pragma unroll
    for (int o = 32; o; o >>= 1) ss += __shfl_xor(ss, o);
    float r = rsqrtf(ss * (1.0f / DI) + EPSF);
    const float4 w = *(const float4*)(gw + lane * 4);
    float4 o;
    o.x = g.x * r * w.x;
    o.y = g.y * r * w.y;
    o.z = g.z * r * w.z;
    o.w = g.w * r * w.w;
    *(float4*)yr = o;
}

// ---------------- 7. GEMM2 + residual: out = x + yn @ W2^T ---------------------
__global__ __launch_bounds__(256) void k_gemm2(const float* __restrict__ A,
                                               const float* __restrict__ W,
                                               const float* __restrict__ xin,
                                               float* __restrict__ out) {
    __shared__ float As[64][68];
    __shared__ float Bs[64][68];
    const int t = threadIdx.x;
    const int m0 = blockIdx.x * 64, n0 = blockIdx.y * 64;
    const int tm = t >> 4, tn = t & 15;
    float acc[4][4] = {};
    for (int k0 = 0; k0 < DI; k0 += 64) {
        __syncthreads();
        #pragma unroll
        for (int i = 0; i < 4; i++) {
            int f4 = t + i * 256;
            int m = f4 >> 4, k4 = f4 & 15;
            *(float4*)&As[m][k4 * 4] = *(const float4*)(A + (size_t)(m0 + m) * DI + k0 + k4 * 4);
            *(float4*)&Bs[m][k4 * 4] = *(const float4*)(W + (size_t)(n0 + m) * DI + k0 + k4 * 4);
        }
        __syncthreads();
        #pragma unroll
        for (int k = 0; k < 64; k += 4) {
            float4 a[4], b[4];
            #pragma unroll
            for (int i = 0; i < 4; i++) a[i] = *(const float4*)&As[tm * 4 + i][k];
            #pragma unroll
            for (int i = 0; i < 4; i++) b[i] = *(const float4*)&Bs[tn * 4 + i][k];
            #pragma unroll
            for (int i = 0; i < 4; i++)
                #pragma unroll
                for (int j = 0; j < 4; j++) {
                    acc[i][j] = fmaf(a[i].x, b[j].x, acc[i][j]);
                    acc[i][j] = fmaf(a[i].y, b[j].y, acc[i][j]);
                    acc[i][j] = fmaf(a[i].z, b[j].z, acc[i][j]);
                    acc[i][j] = fmaf(a[i].w, b[j].w, acc[i][j]);
                }
        }
    }
    #pragma unroll
    for (int i = 0; i < 4; i++) {
        int gm = m0 + tm * 4 + i;
        float4 xv = *(const float4*)(xin + (size_t)gm * DM + n0 + tn * 4);
        float4 o;
        o.x = xv.x + acc[i][0];
        o.y = xv.y + acc[i][1];
        o.z = xv.z + acc[i][2];
        o.w = xv.w + acc[i][3];
        *(float4*)(out + (size_t)gm * DM + n0 + tn * 4) = o;
    }
}

extern "C" void kernel_launch(void* const* d_in, const int* in_sizes, int n_in,
                              void* d_out, int out_size, void* d_ws, size_t ws_size,
                              hipStream_t stream) {
    const float* x   = (const float*)d_in[0];
    const float* nw  = (const float*)d_in[1];
    const float* w1  = (const float*)d_in[2];
    const float* cw  = (const float*)d_in[3];
    const float* cb  = (const float*)d_in[4];
    const float* dtb = (const float*)d_in[5];
    const float* al  = (const float*)d_in[6];
    const float* Dw  = (const float*)d_in[7];
    const float* gw  = (const float*)d_in[8];
    const float* w2  = (const float*)d_in[9];
    float* out = (float*)d_out;

    float* ws = (float*)d_ws;
    float*  zx  = ws;                                   // 32768*648
    float*  xc  = zx + (size_t)NTOK * DPROJ;            // 32768*384
    float2* dtp = (float2*)(xc + (size_t)NTOK * CDIM);  // 32768*8 float2
    float*  yb  = (float*)(dtp + (size_t)NTOK * NH);    // 32768*256
    float*  hst = yb + (size_t)NTOK * DI;               // 64*64*2048
    float*  dAp = hst + (size_t)NB * NH * NC * 2048;    // 64*64
    float*  xn  = yb;                                   // alias: xn dead before yb live

    k_rmsnorm<<<NTOK / 4, 256, 0, stream>>>(x, nw, xn);
    k_gemm1<<<dim3(NTOK / 64, (DPROJ + 63) / 64), 256, 0, stream>>>(xn, w1, zx);
    k_conv<<<(NTOK * CDIM) / 256, 256, 0, stream>>>(zx, cw, cb, xc);
    k_dt<<<(NTOK * NH) / 256, 256, 0, stream>>>(zx, dtb, al, dtp);
    k_ssm1<<<NB * NH * (NC / 4), 256, 0, stream>>>(xc, dtp, hst, dAp);
    k_ssm2<<<NB * NH * 8, 256, 0, stream>>>(hst, dAp);
    k_ssm3<<<NB * NH * (NC / 4), 256, 0, stream>>>(xc, dtp, hst, Dw, yb);
    k_gate<<<NTOK / 4, 256, 0, stream>>>(yb, zx, gw);
    k_gemm2<<<dim3(NTOK / 64, DM / 64), 256, 0, stream>>>(yb, w2, x, out);
}

// Round 4
// 697.867 us; speedup vs baseline: 4.8345x; 1.0888x over previous
//
#include <hip/hip_runtime.h>

#define DM    128
#define DI    256
#define NH    8
#define HD    32
#define NS    64
#define CDIM  384
#define DPROJ 648
#define LSEQ  4096
#define NB    8
#define NTOK  32768          // NB*LSEQ
#define LC    64             // chunk length
#define NC    64             // chunks per (b,h) sequence
#define EPSF  1e-5f

typedef __bf16 bf16;
typedef bf16  bf16x8 __attribute__((ext_vector_type(8)));
typedef short short8 __attribute__((ext_vector_type(8)));
typedef float f32x4  __attribute__((ext_vector_type(4)));

__device__ __forceinline__ unsigned short f2bfbits(float f) {
    unsigned int u = __float_as_uint(f);
    unsigned int r = u + 0x7FFFu + ((u >> 16) & 1u);   // RNE
    return (unsigned short)(r >> 16);
}

// ---------------- 0. fp32 -> bf16 weight cast ----------------------------------
__global__ __launch_bounds__(256) void k_cast(const float* __restrict__ in,
                                              unsigned short* __restrict__ out, int n) {
    int i = blockIdx.x * 256 + threadIdx.x;
    if (i < n) out[i] = f2bfbits(in[i]);
}

// ---------------- 1. input RMSNorm: xn (fp32 + bf16 copies) --------------------
__global__ __launch_bounds__(256) void k_rmsnorm(const float* __restrict__ x,
                                                 const float* __restrict__ w,
                                                 float* __restrict__ xnf,
                                                 unsigned short* __restrict__ xnb) {
    int gid = blockIdx.x * 256 + threadIdx.x;
    int row = gid >> 6, lane = gid & 63;
    const float* xr = x + (size_t)row * DM + lane * 2;
    float v0 = xr[0], v1 = xr[1];
    float ss = v0 * v0 + v1 * v1;
    #pragma unroll
    for (int o = 32; o; o >>= 1) ss += __shfl_xor(ss, o);
    float r = rsqrtf(ss * (1.0f / DM) + EPSF);
    float o0 = v0 * r * w[lane * 2], o1 = v1 * r * w[lane * 2 + 1];
    float* of = xnf + (size_t)row * DM + lane * 2;
    of[0] = o0; of[1] = o1;
    ushort2 ob; ob.x = f2bfbits(o0); ob.y = f2bfbits(o1);
    *(ushort2*)(xnb + (size_t)row * DM + lane * 2) = ob;
}

// ---------------- 2. GEMM1 (bf16 MFMA): zx[M,648] = xnb @ w1b^T ----------------
// 64x64 tile, BK=32, 4 waves each 32x32 (2x2 of 16x16x32 mfma)
__global__ __launch_bounds__(256) void k_gemm1(const unsigned short* __restrict__ A,
                                               const unsigned short* __restrict__ B,
                                               float* __restrict__ C) {
    __shared__ bf16 As[64 * 40];
    __shared__ bf16 Bs[64 * 40];
    const int t = threadIdx.x;
    const int m0 = blockIdx.x * 64, n0 = blockIdx.y * 64;
    const int wave = t >> 6, lane = t & 63;
    const int wm = wave >> 1, wn = wave & 1;
    const int fr = lane & 15, fk = (lane >> 4) * 8;
    f32x4 acc[2][2] = {};
    const int r = t >> 2, q = (t & 3) * 8;
    for (int k0 = 0; k0 < DM; k0 += 32) {
        __syncthreads();
        *(short8*)&As[r * 40 + q] = *(const short8*)(A + (size_t)(m0 + r) * DM + k0 + q);
        short8 bv = {};
        if (n0 + r < DPROJ) bv = *(const short8*)(B + (size_t)(n0 + r) * DM + k0 + q);
        *(short8*)&Bs[r * 40 + q] = bv;
        __syncthreads();
        #pragma unroll
        for (int mt = 0; mt < 2; mt++) {
            bf16x8 af = *(const bf16x8*)&As[(wm * 32 + mt * 16 + fr) * 40 + fk];
            #pragma unroll
            for (int nt = 0; nt < 2; nt++) {
                bf16x8 bf = *(const bf16x8*)&Bs[(wn * 32 + nt * 16 + fr) * 40 + fk];
                acc[mt][nt] = __builtin_amdgcn_mfma_f32_16x16x32_bf16(af, bf, acc[mt][nt], 0, 0, 0);
            }
        }
    }
    #pragma unroll
    for (int mt = 0; mt < 2; mt++)
        #pragma unroll
        for (int nt = 0; nt < 2; nt++) {
            int n = n0 + wn * 32 + nt * 16 + fr;
            if (n >= DPROJ) continue;
            #pragma unroll
            for (int rr = 0; rr < 4; rr++) {
                int m = m0 + wm * 32 + mt * 16 + (lane >> 4) * 4 + rr;
                C[(size_t)m * DPROJ + n] = acc[mt][nt][rr];
            }
        }
}

// ---------------- 3. causal depthwise conv (K=4) + SiLU ------------------------
__global__ __launch_bounds__(256) void k_conv(const float* __restrict__ zx,
                                              const float* __restrict__ cw,
                                              const float* __restrict__ cb,
                                              float* __restrict__ xc) {
    int gid = blockIdx.x * 256 + threadIdx.x;
    int c = gid % CDIM;
    int r = gid / CDIM;
    int l = r & (LSEQ - 1);
    float4 wv = *(const float4*)(cw + c * 4);
    float acc = cb[c];
    const float* col = zx + (size_t)r * DPROJ + DI + c;
    acc = fmaf(col[0], wv.w, acc);
    if (l >= 1) acc = fmaf(col[-1 * DPROJ], wv.z, acc);
    if (l >= 2) acc = fmaf(col[-2 * DPROJ], wv.y, acc);
    if (l >= 3) acc = fmaf(col[-3 * DPROJ], wv.x, acc);
    xc[gid] = acc / (1.f + expf(-acc));
}

// ---------------- 4. dt prep (fp32 path, bypasses bf16 GEMM) -------------------
// wave = token; dot(xn[token], W1[640+h]) in fp32, then softplus / exp
__global__ __launch_bounds__(256) void k_dt(const float* __restrict__ xnf,
                                            const float* __restrict__ w1,
                                            const float* __restrict__ dtb,
                                            const float* __restrict__ alog,
                                            float2* __restrict__ dtp) {
    __shared__ float Wd[8][128];
    const int t = threadIdx.x;
    {
        int row = t >> 5, col = (t & 31) * 4;
        *(float4*)&Wd[row][col] = *(const float4*)(w1 + (size_t)(640 + row) * DM + col);
    }
    __syncthreads();
    const int wave = t >> 6, lane = t & 63;
    const int token = blockIdx.x * 4 + wave;
    float2 xv = *(const float2*)(xnf + (size_t)token * DM + lane * 2);
    #pragma unroll
    for (int h = 0; h < 8; h++) {
        float pp = xv.x * Wd[h][lane * 2] + xv.y * Wd[h][lane * 2 + 1];
        #pragma unroll
        for (int o = 32; o; o >>= 1) pp += __shfl_xor(pp, o);
        if (lane == 0) {
            float v = pp + dtb[h];
            float dt = (v > 20.f) ? v : log1pf(expf(v));
            float2 o; o.x = dt; o.y = expf(dt * -expf(alog[h]));
            dtp[(size_t)token * NH + h] = o;
        }
    }
}

// ---------------- 5a. SSM pass 1: per-chunk local end-state + decay product ----
__global__ __launch_bounds__(256) void k_ssm1(const float* __restrict__ xc,
                                              const float2* __restrict__ dtp,
                                              float* __restrict__ hst,
                                              float* __restrict__ dAp) {
    const int bh = blockIdx.x >> 4, cg = blockIdx.x & 15;
    const int b = bh >> 3, h = bh & 7;
    const int wave = threadIdx.x >> 6, lane = threadIdx.x & 63;
    const int c = cg * 4 + wave;
    const int l0 = c * LC;
    const int pg = lane >> 3, j = lane & 7;
    const int pb = pg * 4;
    const int bo = 256 + j * 8, xo = h * HD + pb;
    const float* row = xc + ((size_t)b * LSEQ + l0) * CDIM;
    const float2* dtr = dtp + ((size_t)b * LSEQ + l0) * NH + h;
    float hs[4][8] = {};
    float4 Bv[2][2]; float4 xv[2]; float2 dtv[2];
    #pragma unroll
    for (int s = 0; s < 2; s++) {
        const float* rp = row + s * CDIM;
        Bv[s][0] = *(const float4*)(rp + bo);
        Bv[s][1] = *(const float4*)(rp + bo + 4);
        xv[s] = *(const float4*)(rp + xo);
        dtv[s] = dtr[s * NH];
    }
    float dAprod = 1.f;
    for (int t = 0; t < LC; t++) {
        const int s = t & 1;
        float4 cB0 = Bv[s][0], cB1 = Bv[s][1], cx = xv[s]; float2 cdt = dtv[s];
        int lp = (t + 2 < LC) ? t + 2 : LC - 1;
        const float* rp = row + lp * CDIM;
        Bv[s][0] = *(const float4*)(rp + bo);
        Bv[s][1] = *(const float4*)(rp + bo + 4);
        xv[s] = *(const float4*)(rp + xo);
        dtv[s] = dtr[lp * NH];
        const float dA = cdt.y;
        dAprod *= dA;
        const float cf0 = cdt.x * cx.x, cf1 = cdt.x * cx.y;
        const float cf2 = cdt.x * cx.z, cf3 = cdt.x * cx.w;
        const float Bk[8] = {cB0.x, cB0.y, cB0.z, cB0.w, cB1.x, cB1.y, cB1.z, cB1.w};
        #pragma unroll
        for (int k = 0; k < 8; k++) {
            hs[0][k] = fmaf(hs[0][k], dA, cf0 * Bk[k]);
            hs[1][k] = fmaf(hs[1][k], dA, cf1 * Bk[k]);
            hs[2][k] = fmaf(hs[2][k], dA, cf2 * Bk[k]);
            hs[3][k] = fmaf(hs[3][k], dA, cf3 * Bk[k]);
        }
    }
    float* base = hst + (((size_t)bh * NC + c) << 11);
    #pragma unroll
    for (int i = 0; i < 4; i++) {
        float4 v0 = {hs[i][0], hs[i][1], hs[i][2], hs[i][3]};
        float4 v1 = {hs[i][4], hs[i][5], hs[i][6], hs[i][7]};
        *(float4*)(base + (pb + i) * 64 + j * 8) = v0;
        *(float4*)(base + (pb + i) * 64 + j * 8 + 4) = v1;
    }
    if (lane == 0) dAp[(size_t)bh * NC + c] = dAprod;
}

// ---------------- 5b. SSM pass 2: exclusive scan over chunk states -------------
__global__ __launch_bounds__(256) void k_ssm2(float* __restrict__ hst,
                                              const float* __restrict__ dAp) {
    const int bh = blockIdx.x >> 3, seg = blockIdx.x & 7;
    const int s = seg * 256 + threadIdx.x;
    float* base = hst + ((size_t)bh * NC << 11) + s;
    const float* dap = dAp + (size_t)bh * NC;
    float run = 0.f;
    for (int c = 0; c < NC; c++) {
        float tmp = base[(size_t)c << 11];
        base[(size_t)c << 11] = run;
        run = fmaf(run, dap[c], tmp);
    }
}

// ---------------- 5c. SSM pass 3: re-scan with incoming state, emit y ----------
// y staged in per-wave LDS over 8 t-steps, flushed with full-wave float4 stores
__global__ __launch_bounds__(256) void k_ssm3(const float* __restrict__ xc,
                                              const float2* __restrict__ dtp,
                                              const float* __restrict__ hst,
                                              const float* __restrict__ Dw,
                                              float* __restrict__ yb) {
    __shared__ float Ybuf[4][8][36];
    const int bh = blockIdx.x >> 4, cg = blockIdx.x & 15;
    const int b = bh >> 3, h = bh & 7;
    const int wave = threadIdx.x >> 6, lane = threadIdx.x & 63;
    const int c = cg * 4 + wave;
    const int l0 = c * LC;
    const int pg = lane >> 3, j = lane & 7;
    const int pb = pg * 4;
    const int bo = 256 + j * 8, co = 320 + j * 8, xo = h * HD + pb;
    const float Dh = Dw[h];
    const float* row = xc + ((size_t)b * LSEQ + l0) * CDIM;
    const float2* dtr = dtp + ((size_t)b * LSEQ + l0) * NH + h;
    float hs[4][8];
    const float* hbase = hst + (((size_t)bh * NC + c) << 11);
    #pragma unroll
    for (int i = 0; i < 4; i++) {
        float4 v0 = *(const float4*)(hbase + (pb + i) * 64 + j * 8);
        float4 v1 = *(const float4*)(hbase + (pb + i) * 64 + j * 8 + 4);
        hs[i][0] = v0.x; hs[i][1] = v0.y; hs[i][2] = v0.z; hs[i][3] = v0.w;
        hs[i][4] = v1.x; hs[i][5] = v1.y; hs[i][6] = v1.z; hs[i][7] = v1.w;
    }
    float4 Bv[2][2], Cv[2][2]; float4 xv[2]; float2 dtv[2];
    #pragma unroll
    for (int s = 0; s < 2; s++) {
        const float* rp = row + s * CDIM;
        Bv[s][0] = *(const float4*)(rp + bo);
        Bv[s][1] = *(const float4*)(rp + bo + 4);
        Cv[s][0] = *(const float4*)(rp + co);
        Cv[s][1] = *(const float4*)(rp + co + 4);
        xv[s] = *(const float4*)(rp + xo);
        dtv[s] = dtr[s * NH];
    }
    float* ybase = yb + ((size_t)b * LSEQ + l0) * DI + h * HD;
    for (int t = 0; t < LC; t++) {
        const int s = t & 1;
        float4 cB0 = Bv[s][0], cB1 = Bv[s][1];
        float4 cC0 = Cv[s][0], cC1 = Cv[s][1];
        float4 cx = xv[s]; float2 cdt = dtv[s];
        int lp = (t + 2 < LC) ? t + 2 : LC - 1;
        const float* rp = row + lp * CDIM;
        Bv[s][0] = *(const float4*)(rp + bo);
        Bv[s][1] = *(const float4*)(rp + bo + 4);
        Cv[s][0] = *(const float4*)(rp + co);
        Cv[s][1] = *(const float4*)(rp + co + 4);
        xv[s] = *(const float4*)(rp + xo);
        dtv[s] = dtr[lp * NH];
        const float dA = cdt.y;
        const float cf0 = cdt.x * cx.x, cf1 = cdt.x * cx.y;
        const float cf2 = cdt.x * cx.z, cf3 = cdt.x * cx.w;
        const float Bk[8] = {cB0.x, cB0.y, cB0.z, cB0.w, cB1.x, cB1.y, cB1.z, cB1.w};
        const float Ck[8] = {cC0.x, cC0.y, cC0.z, cC0.w, cC1.x, cC1.y, cC1.z, cC1.w};
        float y0 = 0.f, y1 = 0.f, y2 = 0.f, y3 = 0.f;
        #pragma unroll
        for (int k = 0; k < 8; k++) {
            hs[0][k] = fmaf(hs[0][k], dA, cf0 * Bk[k]);
            hs[1][k] = fmaf(hs[1][k], dA, cf1 * Bk[k]);
            hs[2][k] = fmaf(hs[2][k], dA, cf2 * Bk[k]);
            hs[3][k] = fmaf(hs[3][k], dA, cf3 * Bk[k]);
            y0 = fmaf(hs[0][k], Ck[k], y0);
            y1 = fmaf(hs[1][k], Ck[k], y1);
            y2 = fmaf(hs[2][k], Ck[k], y2);
            y3 = fmaf(hs[3][k], Ck[k], y3);
        }
        #pragma unroll
        for (int o = 1; o <= 4; o <<= 1) {
            y0 += __shfl_xor(y0, o);
            y1 += __shfl_xor(y1, o);
            y2 += __shfl_xor(y2, o);
            y3 += __shfl_xor(y3, o);
        }
        if (j == 0) {
            float4 yo;
            yo.x = fmaf(Dh, cx.x, y0);
            yo.y = fmaf(Dh, cx.y, y1);
            yo.z = fmaf(Dh, cx.z, y2);
            yo.w = fmaf(Dh, cx.w, y3);
            *(float4*)&Ybuf[wave][t & 7][pb] = yo;
        }
        if ((t & 7) == 7) {
            float4 v = *(const float4*)&Ybuf[wave][lane >> 3][(lane & 7) * 4];
            *(float4*)(ybase + (size_t)(t - 7 + (lane >> 3)) * DI + (lane & 7) * 4) = v;
        }
    }
}

// ---------------- 6. gated RMSNorm -> bf16 -------------------------------------
__global__ __launch_bounds__(256) void k_gate(const float* __restrict__ yb,
                                              const float* __restrict__ zx,
                                              const float* __restrict__ gw,
                                              unsigned short* __restrict__ ynb) {
    int gid = blockIdx.x * 256 + threadIdx.x;
    int row = gid >> 6, lane = gid & 63;
    const float* yr = yb + (size_t)row * DI + lane * 4;
    const float* zr = zx + (size_t)row * DPROJ + lane * 4;
    float4 y = *(const float4*)yr;
    float4 z = *(const float4*)zr;
    float4 g;
    g.x = y.x * (z.x / (1.f + expf(-z.x)));
    g.y = y.y * (z.y / (1.f + expf(-z.y)));
    g.z = y.z * (z.z / (1.f + expf(-z.z)));
    g.w = y.w * (z.w / (1.f + expf(-z.w)));
    float ss = g.x * g.x + g.y * g.y + g.z * g.z + g.w * g.w;
    #pragma unroll
    for (int o = 32; o; o >>= 1) ss += __shfl_xor(ss, o);
    float r = rsqrtf(ss * (1.0f / DI) + EPSF);
    const float4 w = *(const float4*)(gw + lane * 4);
    ushort4 o;
    o.x = f2bfbits(g.x * r * w.x);
    o.y = f2bfbits(g.y * r * w.y);
    o.z = f2bfbits(g.z * r * w.z);
    o.w = f2bfbits(g.w * r * w.w);
    *(ushort4*)(ynb + (size_t)row * DI + lane * 4) = o;
}

// ---------------- 7. GEMM2 (bf16 MFMA) + residual ------------------------------
__global__ __launch_bounds__(256) void k_gemm2(const unsigned short* __restrict__ A,
                                               const unsigned short* __restrict__ B,
                                               const float* __restrict__ xin,
                                               float* __restrict__ out) {
    __shared__ bf16 As[64 * 40];
    __shared__ bf16 Bs[64 * 40];
    const int t = threadIdx.x;
    const int m0 = blockIdx.x * 64, n0 = blockIdx.y * 64;
    const int wave = t >> 6, lane = t & 63;
    const int wm = wave >> 1, wn = wave & 1;
    const int fr = lane & 15, fk = (lane >> 4) * 8;
    f32x4 acc[2][2] = {};
    const int r = t >> 2, q = (t & 3) * 8;
    for (int k0 = 0; k0 < DI; k0 += 32) {
        __syncthreads();
        *(short8*)&As[r * 40 + q] = *(const short8*)(A + (size_t)(m0 + r) * DI + k0 + q);
        *(short8*)&Bs[r * 40 + q] = *(const short8*)(B + (size_t)(n0 + r) * DI + k0 + q);
        __syncthreads();
        #pragma unroll
        for (int mt = 0; mt < 2; mt++) {
            bf16x8 af = *(const bf16x8*)&As[(wm * 32 + mt * 16 + fr) * 40 + fk];
            #pragma unroll
            for (int nt = 0; nt < 2; nt++) {
                bf16x8 bf = *(const bf16x8*)&Bs[(wn * 32 + nt * 16 + fr) * 40 + fk];
                acc[mt][nt] = __builtin_amdgcn_mfma_f32_16x16x32_bf16(af, bf, acc[mt][nt], 0, 0, 0);
            }
        }
    }
    #pragma unroll
    for (int mt = 0; mt < 2; mt++)
        #pragma unroll
        for (int nt = 0; nt < 2; nt++) {
            int n = n0 + wn * 32 + nt * 16 + fr;
            #pragma unroll
            for (int rr = 0; rr < 4; rr++) {
                int m = m0 + wm * 32 + mt * 16 + (lane >> 4) * 4 + rr;
                out[(size_t)m * DM + n] = xin[(size_t)m * DM + n] + acc[mt][nt][rr];
            }
        }
}

extern "C" void kernel_launch(void* const* d_in, const int* in_sizes, int n_in,
                              void* d_out, int out_size, void* d_ws, size_t ws_size,
                              hipStream_t stream) {
    const float* x   = (const float*)d_in[0];
    const float* nw  = (const float*)d_in[1];
    const float* w1  = (const float*)d_in[2];
    const float* cw  = (const float*)d_in[3];
    const float* cb  = (const float*)d_in[4];
    const float* dtb = (const float*)d_in[5];
    const float* al  = (const float*)d_in[6];
    const float* Dw  = (const float*)d_in[7];
    const float* gw  = (const float*)d_in[8];
    const float* w2  = (const float*)d_in[9];
    float* out = (float*)d_out;

    float* ws = (float*)d_ws;
    float*  zx  = ws;                                   // 32768*648
    float*  xc  = zx + (size_t)NTOK * DPROJ;            // 32768*384
    float2* dtp = (float2*)(xc + (size_t)NTOK * CDIM);  // 32768*8 float2
    float*  yb  = (float*)(dtp + (size_t)NTOK * NH);    // 32768*256
    float*  hst = yb + (size_t)NTOK * DI;               // 64*64*2048
    float*  dAp = hst + (size_t)NB * NH * NC * 2048;    // 64*64
    unsigned short* w1b = (unsigned short*)(dAp + NB * NH * NC);     // 648*128
    unsigned short* w2b = w1b + (size_t)DPROJ * DM;                  // 128*256
    // aliases (lifetimes disjoint):
    float*          xnf = hst;                // fp32 xn; dead before ssm1 writes hst
    unsigned short* xnb = (unsigned short*)yb; // bf16 xn; dead before ssm3 writes yb
    unsigned short* ynb = (unsigned short*)xc; // bf16 gated y; xc dead after ssm3

    k_cast<<<(DPROJ * DM + 255) / 256, 256, 0, stream>>>(w1, w1b, DPROJ * DM);
    k_cast<<<(DM * DI + 255) / 256, 256, 0, stream>>>(w2, w2b, DM * DI);
    k_rmsnorm<<<NTOK / 4, 256, 0, stream>>>(x, nw, xnf, xnb);
    k_gemm1<<<dim3(NTOK / 64, (DPROJ + 63) / 64), 256, 0, stream>>>(xnb, w1b, zx);
    k_conv<<<(NTOK * CDIM) / 256, 256, 0, stream>>>(zx, cw, cb, xc);
    k_dt<<<NTOK / 4, 256, 0, stream>>>(xnf, w1, dtb, al, dtp);
    k_ssm1<<<NB * NH * (NC / 4), 256, 0, stream>>>(xc, dtp, hst, dAp);
    k_ssm2<<<NB * NH * 8, 256, 0, stream>>>(hst, dAp);
    k_ssm3<<<NB * NH * (NC / 4), 256, 0, stream>>>(xc, dtp, hst, Dw, yb);
    k_gate<<<NTOK / 4, 256, 0, stream>>>(yb, zx, gw, ynb);
    k_gemm2<<<dim3(NTOK / 64, DM / 64), 256, 0, stream>>>(ynb, w2b, x, out);
}

// Round 5
// 301.813 us; speedup vs baseline: 11.1787x; 2.3123x over previous
//
#include <hip/hip_runtime.h>

#define DM    128
#define DI    256
#define NH    8
#define HD    32
#define NS    64
#define CDIM  384
#define DPROJ 648
#define LSEQ  4096
#define NB    8
#define NTOK  32768          // NB*LSEQ
#define LC    64             // chunk length
#define NC    64             // chunks per (b,h) sequence
#define EPSF  1e-5f
#define LOG2E 1.4426950408889634f

typedef __bf16 bf16;
typedef bf16  bf16x8 __attribute__((ext_vector_type(8)));
typedef bf16  bf16x4 __attribute__((ext_vector_type(4)));
typedef short short8 __attribute__((ext_vector_type(8)));
typedef float f32x4  __attribute__((ext_vector_type(4)));

__device__ __forceinline__ unsigned short f2bfbits(float f) {
    unsigned int u = __float_as_uint(f);
    unsigned int r = u + 0x7FFFu + ((u >> 16) & 1u);   // RNE
    return (unsigned short)(r >> 16);
}
__device__ __forceinline__ bf16x8 cvt8(float4 a, float4 b) {
    bf16x8 r;
    r[0] = (bf16)a.x; r[1] = (bf16)a.y; r[2] = (bf16)a.z; r[3] = (bf16)a.w;
    r[4] = (bf16)b.x; r[5] = (bf16)b.y; r[6] = (bf16)b.z; r[7] = (bf16)b.w;
    return r;
}

// ---------------- 0. fp32 -> bf16 weight cast ----------------------------------
__global__ __launch_bounds__(256) void k_cast(const float* __restrict__ in,
                                              unsigned short* __restrict__ out, int n) {
    int i = blockIdx.x * 256 + threadIdx.x;
    if (i < n) out[i] = f2bfbits(in[i]);
}

// ---------------- 1. input RMSNorm: xn (fp32 + bf16 copies) --------------------
__global__ __launch_bounds__(256) void k_rmsnorm(const float* __restrict__ x,
                                                 const float* __restrict__ w,
                                                 float* __restrict__ xnf,
                                                 unsigned short* __restrict__ xnb) {
    int gid = blockIdx.x * 256 + threadIdx.x;
    int row = gid >> 6, lane = gid & 63;
    const float* xr = x + (size_t)row * DM + lane * 2;
    float v0 = xr[0], v1 = xr[1];
    float ss = v0 * v0 + v1 * v1;
    #pragma unroll
    for (int o = 32; o; o >>= 1) ss += __shfl_xor(ss, o);
    float r = rsqrtf(ss * (1.0f / DM) + EPSF);
    float o0 = v0 * r * w[lane * 2], o1 = v1 * r * w[lane * 2 + 1];
    float* of = xnf + (size_t)row * DM + lane * 2;
    of[0] = o0; of[1] = o1;
    ushort2 ob; ob.x = f2bfbits(o0); ob.y = f2bfbits(o1);
    *(ushort2*)(xnb + (size_t)row * DM + lane * 2) = ob;
}

// ---------------- 2. GEMM1 (bf16 MFMA): zx[M,648] = xnb @ w1b^T ----------------
__global__ __launch_bounds__(256) void k_gemm1(const unsigned short* __restrict__ A,
                                               const unsigned short* __restrict__ B,
                                               float* __restrict__ C) {
    __shared__ bf16 As[64 * 40];
    __shared__ bf16 Bs[64 * 40];
    const int t = threadIdx.x;
    const int m0 = blockIdx.x * 64, n0 = blockIdx.y * 64;
    const int wave = t >> 6, lane = t & 63;
    const int wm = wave >> 1, wn = wave & 1;
    const int fr = lane & 15, fk = (lane >> 4) * 8;
    f32x4 acc[2][2] = {};
    const int r = t >> 2, q = (t & 3) * 8;
    for (int k0 = 0; k0 < DM; k0 += 32) {
        __syncthreads();
        *(short8*)&As[r * 40 + q] = *(const short8*)(A + (size_t)(m0 + r) * DM + k0 + q);
        short8 bv = {};
        if (n0 + r < DPROJ) bv = *(const short8*)(B + (size_t)(n0 + r) * DM + k0 + q);
        *(short8*)&Bs[r * 40 + q] = bv;
        __syncthreads();
        #pragma unroll
        for (int mt = 0; mt < 2; mt++) {
            bf16x8 af = *(const bf16x8*)&As[(wm * 32 + mt * 16 + fr) * 40 + fk];
            #pragma unroll
            for (int nt = 0; nt < 2; nt++) {
                bf16x8 bf = *(const bf16x8*)&Bs[(wn * 32 + nt * 16 + fr) * 40 + fk];
                acc[mt][nt] = __builtin_amdgcn_mfma_f32_16x16x32_bf16(af, bf, acc[mt][nt], 0, 0, 0);
            }
        }
    }
    #pragma unroll
    for (int mt = 0; mt < 2; mt++)
        #pragma unroll
        for (int nt = 0; nt < 2; nt++) {
            int n = n0 + wn * 32 + nt * 16 + fr;
            if (n >= DPROJ) continue;
            #pragma unroll
            for (int rr = 0; rr < 4; rr++) {
                int m = m0 + wm * 32 + mt * 16 + (lane >> 4) * 4 + rr;
                C[(size_t)m * DPROJ + n] = acc[mt][nt][rr];
            }
        }
}

// ---------------- 3. causal depthwise conv (K=4) + SiLU ------------------------
__global__ __launch_bounds__(256) void k_conv(const float* __restrict__ zx,
                                              const float* __restrict__ cw,
                                              const float* __restrict__ cb,
                                              float* __restrict__ xc) {
    int gid = blockIdx.x * 256 + threadIdx.x;
    int c = gid % CDIM;
    int r = gid / CDIM;
    int l = r & (LSEQ - 1);
    float4 wv = *(const float4*)(cw + c * 4);
    float acc = cb[c];
    const float* col = zx + (size_t)r * DPROJ + DI + c;
    acc = fmaf(col[0], wv.w, acc);
    if (l >= 1) acc = fmaf(col[-1 * DPROJ], wv.z, acc);
    if (l >= 2) acc = fmaf(col[-2 * DPROJ], wv.y, acc);
    if (l >= 3) acc = fmaf(col[-3 * DPROJ], wv.x, acc);
    xc[gid] = acc / (1.f + expf(-acc));
}

// ---------------- 4. dt prep (fp32 path): dtf = softplus(xn.W1d + bias) --------
__global__ __launch_bounds__(256) void k_dt(const float* __restrict__ xnf,
                                            const float* __restrict__ w1,
                                            const float* __restrict__ dtb,
                                            float* __restrict__ dtf) {
    __shared__ float Wd[8][128];
    const int t = threadIdx.x;
    {
        int row = t >> 5, col = (t & 31) * 4;
        *(float4*)&Wd[row][col] = *(const float4*)(w1 + (size_t)(640 + row) * DM + col);
    }
    __syncthreads();
    const int wave = t >> 6, lane = t & 63;
    const int token = blockIdx.x * 4 + wave;
    float2 xv = *(const float2*)(xnf + (size_t)token * DM + lane * 2);
    #pragma unroll
    for (int h = 0; h < 8; h++) {
        float pp = xv.x * Wd[h][lane * 2] + xv.y * Wd[h][lane * 2 + 1];
        #pragma unroll
        for (int o = 32; o; o >>= 1) pp += __shfl_xor(pp, o);
        if (lane == 0) {
            float v = pp + dtb[h];
            dtf[(size_t)token * NH + h] = (v > 20.f) ? v : log1pf(expf(v));
        }
    }
}

// ---------------- 5a. SSD pass 1: chunk-local end state via MFMA ---------------
// wave = one chunk. h_local[n][p] = sum_t w_t*B[t,n]*X[t,p], w_t = 2^(qL-q_t)*dt_t
__global__ __launch_bounds__(256, 2) void k_ssd1(const float* __restrict__ xc,
                                                 const float* __restrict__ dtf,
                                                 const float* __restrict__ alog,
                                                 float* __restrict__ hst,
                                                 float* __restrict__ dAp) {
    __shared__ bf16 Wl[4][64 * 72];
    __shared__ bf16 Xl[4][64 * 36];
    __shared__ float wl[4][64];
    const int bh = blockIdx.x >> 4, cg = blockIdx.x & 15;
    const int b = bh >> 3, h = bh & 7;
    const int wave = threadIdx.x >> 6, lane = threadIdx.x & 63;
    const int c = cg * 4 + wave;
    const size_t tok0 = (size_t)b * LSEQ + c * LC;
    const float A = -expf(alog[h]);
    // q-scan (inclusive cumsum of dt*A*log2e over 64 lanes)
    float dt = dtf[(tok0 + lane) * NH + h];
    float q = dt * A * LOG2E;
    #pragma unroll
    for (int o = 1; o <= 32; o <<= 1) {
        float tmp = __shfl_up(q, o);
        if (lane >= o) q += tmp;
    }
    float qL = __shfl(q, 63);
    wl[wave][lane] = exp2f(qL - q) * dt;
    // stage X[t][p] bf16
    const float* xrow = xc + tok0 * CDIM;
    #pragma unroll
    for (int it = 0; it < 8; it++) {
        int f = it * 64 + lane, r = f >> 3, c4 = (f & 7) * 4;
        float4 v = *(const float4*)(xrow + (size_t)r * CDIM + h * HD + c4);
        bf16x4 o; o[0] = (bf16)v.x; o[1] = (bf16)v.y; o[2] = (bf16)v.z; o[3] = (bf16)v.w;
        *(bf16x4*)&Xl[wave][r * 36 + c4] = o;
    }
    // stage (w o B)[t][n] bf16
    #pragma unroll
    for (int it = 0; it < 16; it++) {
        int f = it * 64 + lane, r = f >> 4, c4 = (f & 15) * 4;
        float w = wl[wave][r];
        float4 v = *(const float4*)(xrow + (size_t)r * CDIM + 256 + c4);
        bf16x4 o; o[0] = (bf16)(v.x * w); o[1] = (bf16)(v.y * w);
        o[2] = (bf16)(v.z * w); o[3] = (bf16)(v.w * w);
        *(bf16x4*)&Wl[wave][r * 72 + c4] = o;
    }
    const int m = lane & 15, ko = lane >> 4;
    f32x4 hacc[4][2] = {};
    #pragma unroll
    for (int kh = 0; kh < 2; kh++) {
        bf16x8 xb[2];
        #pragma unroll
        for (int pi = 0; pi < 2; pi++)
            #pragma unroll
            for (int j = 0; j < 8; j++)
                xb[pi][j] = Xl[wave][(kh * 32 + ko * 8 + j) * 36 + pi * 16 + m];
        #pragma unroll
        for (int ni = 0; ni < 4; ni++) {
            bf16x8 af;
            #pragma unroll
            for (int j = 0; j < 8; j++)
                af[j] = Wl[wave][(kh * 32 + ko * 8 + j) * 72 + ni * 16 + m];
            #pragma unroll
            for (int pi = 0; pi < 2; pi++)
                hacc[ni][pi] = __builtin_amdgcn_mfma_f32_16x16x32_bf16(af, xb[pi], hacc[ni][pi], 0, 0, 0);
        }
    }
    float* hb = hst + (((size_t)bh * NC + c) << 11);
    #pragma unroll
    for (int ni = 0; ni < 4; ni++)
        #pragma unroll
        for (int pi = 0; pi < 2; pi++)
            #pragma unroll
            for (int r = 0; r < 4; r++)
                hb[(ni * 16 + ko * 4 + r) * 32 + pi * 16 + m] = hacc[ni][pi][r];
    if (lane == 0) dAp[(size_t)bh * NC + c] = exp2f(qL);
}

// ---------------- 5b. SSM pass 2: exclusive scan over chunk states -------------
__global__ __launch_bounds__(256) void k_ssm2(float* __restrict__ hst,
                                              const float* __restrict__ dAp) {
    const int bh = blockIdx.x >> 3, seg = blockIdx.x & 7;
    const int s = seg * 256 + threadIdx.x;
    float* base = hst + ((size_t)bh * NC << 11) + s;
    const float* dap = dAp + (size_t)bh * NC;
    float run = 0.f;
    for (int c = 0; c < NC; c++) {
        float tmp = base[(size_t)c << 11];
        base[(size_t)c << 11] = run;
        run = fmaf(run, dap[c], tmp);
    }
}

// ---------------- 5c. SSD pass 3: Y = P.X + diag(2^q).(C.h_in^T) ---------------
// P[t,s] = (C_t.B_s) * 2^(q_t-q_s) * dt_s  (causal), P[t,t] += D
__global__ __launch_bounds__(256, 2) void k_ssd3(const float* __restrict__ xc,
                                                 const float* __restrict__ dtf,
                                                 const float* __restrict__ alog,
                                                 const float* __restrict__ hst,
                                                 const float* __restrict__ Dw,
                                                 float* __restrict__ yb) {
    __shared__ bf16 Pl[4][64 * 72];
    __shared__ bf16 Xl[4][64 * 36];
    __shared__ bf16 Hl[4][64 * 36];
    __shared__ float ql[4][64];
    __shared__ float dl[4][64];
    const int bh = blockIdx.x >> 4, cg = blockIdx.x & 15;
    const int b = bh >> 3, h = bh & 7;
    const int wave = threadIdx.x >> 6, lane = threadIdx.x & 63;
    const int c = cg * 4 + wave;
    const size_t tok0 = (size_t)b * LSEQ + c * LC;
    const float A = -expf(alog[h]);
    const float Dh = Dw[h];
    // q-scan
    float dt = dtf[(tok0 + lane) * NH + h];
    float q = dt * A * LOG2E;
    #pragma unroll
    for (int o = 1; o <= 32; o <<= 1) {
        float tmp = __shfl_up(q, o);
        if (lane >= o) q += tmp;
    }
    ql[wave][lane] = q;
    dl[wave][lane] = dt;
    // stage X[t][p]
    const float* xrow = xc + tok0 * CDIM;
    #pragma unroll
    for (int it = 0; it < 8; it++) {
        int f = it * 64 + lane, r = f >> 3, c4 = (f & 7) * 4;
        float4 v = *(const float4*)(xrow + (size_t)r * CDIM + h * HD + c4);
        bf16x4 o; o[0] = (bf16)v.x; o[1] = (bf16)v.y; o[2] = (bf16)v.z; o[3] = (bf16)v.w;
        *(bf16x4*)&Xl[wave][r * 36 + c4] = o;
    }
    // stage h_in[n][p]
    const float* hbg = hst + (((size_t)bh * NC + c) << 11);
    #pragma unroll
    for (int it = 0; it < 8; it++) {
        int f = it * 64 + lane, r = f >> 3, c4 = (f & 7) * 4;
        float4 v = *(const float4*)(hbg + r * 32 + c4);
        bf16x4 o; o[0] = (bf16)v.x; o[1] = (bf16)v.y; o[2] = (bf16)v.z; o[3] = (bf16)v.w;
        *(bf16x4*)&Hl[wave][r * 36 + c4] = o;
    }
    const int m = lane & 15, ko = lane >> 4;
    // C frags (A-operand), reused for G and U
    bf16x8 cf[4][2];
    #pragma unroll
    for (int ti = 0; ti < 4; ti++)
        #pragma unroll
        for (int kh = 0; kh < 2; kh++) {
            const float* p = xrow + (size_t)(ti * 16 + m) * CDIM + 320 + kh * 32 + ko * 8;
            cf[ti][kh] = cvt8(*(const float4*)p, *(const float4*)(p + 4));
        }
    // G = C.B^T
    f32x4 g[4][4] = {};
    #pragma unroll
    for (int kh = 0; kh < 2; kh++) {
        bf16x8 bfg[4];
        #pragma unroll
        for (int si = 0; si < 4; si++) {
            const float* p = xrow + (size_t)(si * 16 + m) * CDIM + 256 + kh * 32 + ko * 8;
            bfg[si] = cvt8(*(const float4*)p, *(const float4*)(p + 4));
        }
        #pragma unroll
        for (int ti = 0; ti < 4; ti++)
            #pragma unroll
            for (int si = 0; si < 4; si++)
                g[ti][si] = __builtin_amdgcn_mfma_f32_16x16x32_bf16(cf[ti][kh], bfg[si], g[ti][si], 0, 0, 0);
    }
    // P = G o W (+ D on diag), bf16 into LDS
    float qt[4][4], et[4][4];
    #pragma unroll
    for (int ti = 0; ti < 4; ti++)
        #pragma unroll
        for (int r = 0; r < 4; r++) {
            float v = ql[wave][ti * 16 + ko * 4 + r];
            qt[ti][r] = v; et[ti][r] = exp2f(v);
        }
    float qs[4], ds[4];
    #pragma unroll
    for (int si = 0; si < 4; si++) {
        qs[si] = ql[wave][si * 16 + m];
        ds[si] = dl[wave][si * 16 + m];
    }
    #pragma unroll
    for (int ti = 0; ti < 4; ti++)
        #pragma unroll
        for (int si = 0; si < 4; si++)
            #pragma unroll
            for (int r = 0; r < 4; r++) {
                int t = ti * 16 + ko * 4 + r, s = si * 16 + m;
                float p = 0.f;
                if (si <= ti) {
                    float w = (s <= t) ? exp2f(qt[ti][r] - qs[si]) * ds[si] : 0.f;
                    p = g[ti][si][r] * w;
                    if (s == t) p += Dh;
                }
                Pl[wave][t * 72 + s] = (bf16)p;
            }
    // Y = P.X + diag(et).(C.h_in^T)
    f32x4 ya[4][2] = {}, ua[4][2] = {};
    #pragma unroll
    for (int kh = 0; kh < 2; kh++) {
        bf16x8 xb[2], hb2[2];
        #pragma unroll
        for (int pi = 0; pi < 2; pi++)
            #pragma unroll
            for (int j = 0; j < 8; j++) {
                int kk = kh * 32 + ko * 8 + j;
                xb[pi][j]  = Xl[wave][kk * 36 + pi * 16 + m];
                hb2[pi][j] = Hl[wave][kk * 36 + pi * 16 + m];
            }
        #pragma unroll
        for (int ti = 0; ti < 4; ti++) {
            bf16x8 pa = *(const bf16x8*)&Pl[wave][(ti * 16 + m) * 72 + kh * 32 + ko * 8];
            #pragma unroll
            for (int pi = 0; pi < 2; pi++) {
                ya[ti][pi] = __builtin_amdgcn_mfma_f32_16x16x32_bf16(pa, xb[pi], ya[ti][pi], 0, 0, 0);
                ua[ti][pi] = __builtin_amdgcn_mfma_f32_16x16x32_bf16(cf[ti][kh], hb2[pi], ua[ti][pi], 0, 0, 0);
            }
        }
    }
    float* yrow = yb + tok0 * DI + h * HD;
    #pragma unroll
    for (int ti = 0; ti < 4; ti++)
        #pragma unroll
        for (int pi = 0; pi < 2; pi++)
            #pragma unroll
            for (int r = 0; r < 4; r++) {
                int t = ti * 16 + ko * 4 + r;
                yrow[(size_t)t * DI + pi * 16 + m] = ya[ti][pi][r] + et[ti][r] * ua[ti][pi][r];
            }
}

// ---------------- 6. gated RMSNorm -> bf16 -------------------------------------
__global__ __launch_bounds__(256) void k_gate(const float* __restrict__ yb,
                                              const float* __restrict__ zx,
                                              const float* __restrict__ gw,
                                              unsigned short* __restrict__ ynb) {
    int gid = blockIdx.x * 256 + threadIdx.x;
    int row = gid >> 6, lane = gid & 63;
    const float* yr = yb + (size_t)row * DI + lane * 4;
    const float* zr = zx + (size_t)row * DPROJ + lane * 4;
    float4 y = *(const float4*)yr;
    float4 z = *(const float4*)zr;
    float4 g;
    g.x = y.x * (z.x / (1.f + expf(-z.x)));
    g.y = y.y * (z.y / (1.f + expf(-z.y)));
    g.z = y.z * (z.z / (1.f + expf(-z.z)));
    g.w = y.w * (z.w / (1.f + expf(-z.w)));
    float ss = g.x * g.x + g.y * g.y + g.z * g.z + g.w * g.w;
    #pragma unroll
    for (int o = 32; o; o >>= 1) ss += __shfl_xor(ss, o);
    float r = rsqrtf(ss * (1.0f / DI) + EPSF);
    const float4 w = *(const float4*)(gw + lane * 4);
    ushort4 o;
    o.x = f2bfbits(g.x * r * w.x);
    o.y = f2bfbits(g.y * r * w.y);
    o.z = f2bfbits(g.z * r * w.z);
    o.w = f2bfbits(g.w * r * w.w);
    *(ushort4*)(ynb + (size_t)row * DI + lane * 4) = o;
}

// ---------------- 7. GEMM2 (bf16 MFMA) + residual ------------------------------
__global__ __launch_bounds__(256) void k_gemm2(const unsigned short* __restrict__ A,
                                               const unsigned short* __restrict__ B,
                                               const float* __restrict__ xin,
                                               float* __restrict__ out) {
    __shared__ bf16 As[64 * 40];
    __shared__ bf16 Bs[64 * 40];
    const int t = threadIdx.x;
    const int m0 = blockIdx.x * 64, n0 = blockIdx.y * 64;
    const int wave = t >> 6, lane = t & 63;
    const int wm = wave >> 1, wn = wave & 1;
    const int fr = lane & 15, fk = (lane >> 4) * 8;
    f32x4 acc[2][2] = {};
    const int r = t >> 2, q = (t & 3) * 8;
    for (int k0 = 0; k0 < DI; k0 += 32) {
        __syncthreads();
        *(short8*)&As[r * 40 + q] = *(const short8*)(A + (size_t)(m0 + r) * DI + k0 + q);
        *(short8*)&Bs[r * 40 + q] = *(const short8*)(B + (size_t)(n0 + r) * DI + k0 + q);
        __syncthreads();
        #pragma unroll
        for (int mt = 0; mt < 2; mt++) {
            bf16x8 af = *(const bf16x8*)&As[(wm * 32 + mt * 16 + fr) * 40 + fk];
            #pragma unroll
            for (int nt = 0; nt < 2; nt++) {
                bf16x8 bf = *(const bf16x8*)&Bs[(wn * 32 + nt * 16 + fr) * 40 + fk];
                acc[mt][nt] = __builtin_amdgcn_mfma_f32_16x16x32_bf16(af, bf, acc[mt][nt], 0, 0, 0);
            }
        }
    }
    #pragma unroll
    for (int mt = 0; mt < 2; mt++)
        #pragma unroll
        for (int nt = 0; nt < 2; nt++) {
            int n = n0 + wn * 32 + nt * 16 + fr;
            #pragma unroll
            for (int rr = 0; rr < 4; rr++) {
                int m = m0 + wm * 32 + mt * 16 + (lane >> 4) * 4 + rr;
                out[(size_t)m * DM + n] = xin[(size_t)m * DM + n] + acc[mt][nt][rr];
            }
        }
}

extern "C" void kernel_launch(void* const* d_in, const int* in_sizes, int n_in,
                              void* d_out, int out_size, void* d_ws, size_t ws_size,
                              hipStream_t stream) {
    const float* x   = (const float*)d_in[0];
    const float* nw  = (const float*)d_in[1];
    const float* w1  = (const float*)d_in[2];
    const float* cw  = (const float*)d_in[3];
    const float* cb  = (const float*)d_in[4];
    const float* dtb = (const float*)d_in[5];
    const float* al  = (const float*)d_in[6];
    const float* Dw  = (const float*)d_in[7];
    const float* gw  = (const float*)d_in[8];
    const float* w2  = (const float*)d_in[9];
    float* out = (float*)d_out;

    float* ws = (float*)d_ws;
    float*  zx  = ws;                                   // 32768*648
    float*  xc  = zx + (size_t)NTOK * DPROJ;            // 32768*384
    float*  dtf = xc + (size_t)NTOK * CDIM;             // 32768*8 (region sized 2x)
    float*  yb  = dtf + (size_t)NTOK * NH * 2;          // 32768*256
    float*  hst = yb + (size_t)NTOK * DI;               // 64*64*2048
    float*  dAp = hst + (size_t)NB * NH * NC * 2048;    // 64*64
    unsigned short* w1b = (unsigned short*)(dAp + NB * NH * NC);     // 648*128
    unsigned short* w2b = w1b + (size_t)DPROJ * DM;                  // 128*256
    // aliases (lifetimes disjoint):
    float*          xnf = hst;                 // fp32 xn; dead before ssd1 writes hst
    unsigned short* xnb = (unsigned short*)yb; // bf16 xn; dead before ssd3 writes yb
    unsigned short* ynb = (unsigned short*)xc; // bf16 gated y; xc dead after ssd3

    k_cast<<<(DPROJ * DM + 255) / 256, 256, 0, stream>>>(w1, w1b, DPROJ * DM);
    k_cast<<<(DM * DI + 255) / 256, 256, 0, stream>>>(w2, w2b, DM * DI);
    k_rmsnorm<<<NTOK / 4, 256, 0, stream>>>(x, nw, xnf, xnb);
    k_gemm1<<<dim3(NTOK / 64, (DPROJ + 63) / 64), 256, 0, stream>>>(xnb, w1b, zx);
    k_conv<<<(NTOK * CDIM) / 256, 256, 0, stream>>>(zx, cw, cb, xc);
    k_dt<<<NTOK / 4, 256, 0, stream>>>(xnf, w1, dtb, dtf);
    k_ssd1<<<NB * NH * (NC / 4), 256, 0, stream>>>(xc, dtf, al, hst, dAp);
    k_ssm2<<<NB * NH * 8, 256, 0, stream>>>(hst, dAp);
    k_ssd3<<<NB * NH * (NC / 4), 256, 0, stream>>>(xc, dtf, al, hst, Dw, yb);
    k_gate<<<NTOK / 4, 256, 0, stream>>>(yb, zx, gw, ynb);
    k_gemm2<<<dim3(NTOK / 64, DM / 64), 256, 0, stream>>>(ynb, w2b, x, out);
}

// Round 6
// 250.011 us; speedup vs baseline: 13.4948x; 1.2072x over previous
//
#include <hip/hip_runtime.h>

#define DM    128
#define DI    256
#define NH    8
#define HD    32
#define NS    64
#define CDIM  384
#define DPROJ 648
#define LSEQ  4096
#define NB    8
#define NTOK  32768          // NB*LSEQ
#define LC    64             // chunk length
#define NC    64             // chunks per (b,h) sequence
#define EPSF  1e-5f
#define LOG2E 1.4426950408889634f

typedef __bf16 bf16;
typedef bf16  bf16x8 __attribute__((ext_vector_type(8)));
typedef bf16  bf16x4 __attribute__((ext_vector_type(4)));
typedef short short8 __attribute__((ext_vector_type(8)));
typedef float f32x4  __attribute__((ext_vector_type(4)));

__device__ __forceinline__ unsigned short f2bfbits(float f) {
    unsigned int u = __float_as_uint(f);
    unsigned int r = u + 0x7FFFu + ((u >> 16) & 1u);   // RNE
    return (unsigned short)(r >> 16);
}
__device__ __forceinline__ float bfbits2f(unsigned short u) {
    return __uint_as_float(((unsigned int)u) << 16);
}

// ---------------- 0. fp32 -> bf16 weight cast ----------------------------------
__global__ __launch_bounds__(256) void k_cast(const float* __restrict__ in,
                                              unsigned short* __restrict__ out, int n) {
    int i = blockIdx.x * 256 + threadIdx.x;
    if (i < n) out[i] = f2bfbits(in[i]);
}

// ---------------- 1. input RMSNorm: xn (fp32 + bf16 copies) --------------------
__global__ __launch_bounds__(256) void k_rmsnorm(const float* __restrict__ x,
                                                 const float* __restrict__ w,
                                                 float* __restrict__ xnf,
                                                 unsigned short* __restrict__ xnb) {
    int gid = blockIdx.x * 256 + threadIdx.x;
    int row = gid >> 6, lane = gid & 63;
    const float* xr = x + (size_t)row * DM + lane * 2;
    float v0 = xr[0], v1 = xr[1];
    float ss = v0 * v0 + v1 * v1;
    #pragma unroll
    for (int o = 32; o; o >>= 1) ss += __shfl_xor(ss, o);
    float r = rsqrtf(ss * (1.0f / DM) + EPSF);
    float o0 = v0 * r * w[lane * 2], o1 = v1 * r * w[lane * 2 + 1];
    float* of = xnf + (size_t)row * DM + lane * 2;
    of[0] = o0; of[1] = o1;
    ushort2 ob; ob.x = f2bfbits(o0); ob.y = f2bfbits(o1);
    *(ushort2*)(xnb + (size_t)row * DM + lane * 2) = ob;
}

// ---------------- 2. GEMM1 (bf16 MFMA): split bf16 out (z | xBC) ---------------
__global__ __launch_bounds__(256) void k_gemm1(const unsigned short* __restrict__ A,
                                               const unsigned short* __restrict__ B,
                                               unsigned short* __restrict__ zb,
                                               unsigned short* __restrict__ xbc) {
    __shared__ bf16 As[64 * 40];
    __shared__ bf16 Bs[64 * 40];
    const int t = threadIdx.x;
    const int m0 = blockIdx.x * 64, n0 = blockIdx.y * 64;
    const int wave = t >> 6, lane = t & 63;
    const int wm = wave >> 1, wn = wave & 1;
    const int fr = lane & 15, fk = (lane >> 4) * 8;
    f32x4 acc[2][2] = {};
    const int r = t >> 2, q = (t & 3) * 8;
    for (int k0 = 0; k0 < DM; k0 += 32) {
        __syncthreads();
        *(short8*)&As[r * 40 + q] = *(const short8*)(A + (size_t)(m0 + r) * DM + k0 + q);
        short8 bv = {};
        if (n0 + r < DPROJ) bv = *(const short8*)(B + (size_t)(n0 + r) * DM + k0 + q);
        *(short8*)&Bs[r * 40 + q] = bv;
        __syncthreads();
        #pragma unroll
        for (int mt = 0; mt < 2; mt++) {
            bf16x8 af = *(const bf16x8*)&As[(wm * 32 + mt * 16 + fr) * 40 + fk];
            #pragma unroll
            for (int nt = 0; nt < 2; nt++) {
                bf16x8 bf = *(const bf16x8*)&Bs[(wn * 32 + nt * 16 + fr) * 40 + fk];
                acc[mt][nt] = __builtin_amdgcn_mfma_f32_16x16x32_bf16(af, bf, acc[mt][nt], 0, 0, 0);
            }
        }
    }
    #pragma unroll
    for (int mt = 0; mt < 2; mt++)
        #pragma unroll
        for (int nt = 0; nt < 2; nt++) {
            int n = n0 + wn * 32 + nt * 16 + fr;
            if (n >= 640) continue;
            #pragma unroll
            for (int rr = 0; rr < 4; rr++) {
                int m = m0 + wm * 32 + mt * 16 + (lane >> 4) * 4 + rr;
                unsigned short v = f2bfbits(acc[mt][nt][rr]);
                if (n < DI) zb[(size_t)m * DI + n] = v;
                else        xbc[(size_t)m * CDIM + (n - 256)] = v;
            }
        }
}

// ---------------- 3. causal depthwise conv (K=4) + SiLU, bf16 ------------------
// block = 384 threads (one per channel), 64 sequential tokens, reg tap history
__global__ __launch_bounds__(384) void k_conv(const unsigned short* __restrict__ xbc,
                                              const float* __restrict__ cw,
                                              const float* __restrict__ cb,
                                              unsigned short* __restrict__ xcb) {
    const int c = threadIdx.x;
    const int t0 = blockIdx.x * 64;
    const int l0 = t0 & (LSEQ - 1);
    float4 wv = *(const float4*)(cw + c * 4);
    float bias = cb[c];
    const unsigned short* in = xbc + (size_t)t0 * CDIM + c;
    unsigned short* out = xcb + (size_t)t0 * CDIM + c;
    float h1 = 0.f, h2 = 0.f, h3 = 0.f;
    if (l0) {
        h1 = bfbits2f(in[-CDIM]);
        h2 = bfbits2f(in[-2 * CDIM]);
        h3 = bfbits2f(in[-3 * CDIM]);
    }
    #pragma unroll 4
    for (int t = 0; t < 64; t++) {
        float x0 = bfbits2f(in[(size_t)t * CDIM]);
        float acc = bias;
        acc = fmaf(x0, wv.w, acc);
        acc = fmaf(h1, wv.z, acc);
        acc = fmaf(h2, wv.y, acc);
        acc = fmaf(h3, wv.x, acc);
        float s = acc / (1.f + expf(-acc));
        out[(size_t)t * CDIM] = f2bfbits(s);
        h3 = h2; h2 = h1; h1 = x0;
    }
}

// ---------------- 4. dt prep (fp32 path): dtf = softplus(xn.W1d + bias) --------
__global__ __launch_bounds__(256) void k_dt(const float* __restrict__ xnf,
                                            const float* __restrict__ w1,
                                            const float* __restrict__ dtb,
                                            float* __restrict__ dtf) {
    __shared__ float Wd[8][128];
    const int t = threadIdx.x;
    {
        int row = t >> 5, col = (t & 31) * 4;
        *(float4*)&Wd[row][col] = *(const float4*)(w1 + (size_t)(640 + row) * DM + col);
    }
    __syncthreads();
    const int wave = t >> 6, lane = t & 63;
    const int token = blockIdx.x * 4 + wave;
    float2 xv = *(const float2*)(xnf + (size_t)token * DM + lane * 2);
    #pragma unroll
    for (int h = 0; h < 8; h++) {
        float pp = xv.x * Wd[h][lane * 2] + xv.y * Wd[h][lane * 2 + 1];
        #pragma unroll
        for (int o = 32; o; o >>= 1) pp += __shfl_xor(pp, o);
        if (lane == 0) {
            float v = pp + dtb[h];
            dtf[(size_t)token * NH + h] = (v > 20.f) ? v : log1pf(expf(v));
        }
    }
}

// ---------------- 5a. SSD pass 1: chunk-local end state via MFMA ---------------
__global__ __launch_bounds__(256, 2) void k_ssd1(const unsigned short* __restrict__ xcb,
                                                 const float* __restrict__ dtf,
                                                 const float* __restrict__ alog,
                                                 float* __restrict__ hst,
                                                 float* __restrict__ dAp) {
    __shared__ bf16 Wl[4][64 * 72];
    __shared__ bf16 Xl[4][64 * 40];
    __shared__ float wl[4][64];
    const int bh = blockIdx.x >> 4, cg = blockIdx.x & 15;
    const int b = bh >> 3, h = bh & 7;
    const int wave = threadIdx.x >> 6, lane = threadIdx.x & 63;
    const int c = cg * 4 + wave;
    const size_t tok0 = (size_t)b * LSEQ + c * LC;
    const float A = -expf(alog[h]);
    float dt = dtf[(tok0 + lane) * NH + h];
    float q = dt * A * LOG2E;
    #pragma unroll
    for (int o = 1; o <= 32; o <<= 1) {
        float tmp = __shfl_up(q, o);
        if (lane >= o) q += tmp;
    }
    float qL = __shfl(q, 63);
    wl[wave][lane] = exp2f(qL - q) * dt;
    const unsigned short* xrow = xcb + tok0 * CDIM;
    // stage X[t][p] bf16 (straight copy)
    #pragma unroll
    for (int it = 0; it < 4; it++) {
        int f = it * 64 + lane, r = f >> 2, c8 = (f & 3) * 8;
        *(bf16x8*)&Xl[wave][r * 40 + c8] = *(const bf16x8*)(xrow + (size_t)r * CDIM + h * HD + c8);
    }
    // stage (w o B)[t][n] bf16
    #pragma unroll
    for (int it = 0; it < 8; it++) {
        int f = it * 64 + lane, r = f >> 3, c8 = (f & 7) * 8;
        float w = wl[wave][r];
        bf16x8 v = *(const bf16x8*)(xrow + (size_t)r * CDIM + 256 + c8);
        bf16x8 o;
        #pragma unroll
        for (int j = 0; j < 8; j++) o[j] = (bf16)((float)v[j] * w);
        *(bf16x8*)&Wl[wave][r * 72 + c8] = o;
    }
    const int m = lane & 15, ko = lane >> 4;
    f32x4 hacc[4][2] = {};
    #pragma unroll
    for (int kh = 0; kh < 2; kh++) {
        bf16x8 xb[2];
        #pragma unroll
        for (int pi = 0; pi < 2; pi++)
            #pragma unroll
            for (int j = 0; j < 8; j++)
                xb[pi][j] = Xl[wave][(kh * 32 + ko * 8 + j) * 40 + pi * 16 + m];
        #pragma unroll
        for (int ni = 0; ni < 4; ni++) {
            bf16x8 af;
            #pragma unroll
            for (int j = 0; j < 8; j++)
                af[j] = Wl[wave][(kh * 32 + ko * 8 + j) * 72 + ni * 16 + m];
            #pragma unroll
            for (int pi = 0; pi < 2; pi++)
                hacc[ni][pi] = __builtin_amdgcn_mfma_f32_16x16x32_bf16(af, xb[pi], hacc[ni][pi], 0, 0, 0);
        }
    }
    float* hb = hst + (((size_t)bh * NC + c) << 11);
    #pragma unroll
    for (int ni = 0; ni < 4; ni++)
        #pragma unroll
        for (int pi = 0; pi < 2; pi++)
            #pragma unroll
            for (int r = 0; r < 4; r++)
                hb[(ni * 16 + ko * 4 + r) * 32 + pi * 16 + m] = hacc[ni][pi][r];
    if (lane == 0) dAp[(size_t)bh * NC + c] = exp2f(qL);
}

// ---------------- 5b. SSM pass 2: exclusive scan over chunk states -------------
__global__ __launch_bounds__(256) void k_ssm2(float* __restrict__ hst,
                                              const float* __restrict__ dAp) {
    const int bh = blockIdx.x >> 3, seg = blockIdx.x & 7;
    const int s = seg * 256 + threadIdx.x;
    float* base = hst + ((size_t)bh * NC << 11) + s;
    const float* dap = dAp + (size_t)bh * NC;
    float run = 0.f;
    for (int c = 0; c < NC; c++) {
        float tmp = base[(size_t)c << 11];
        base[(size_t)c << 11] = run;
        run = fmaf(run, dap[c], tmp);
    }
}

// ---------------- 5c. SSD pass 3: Y = P.X + diag(2^q).(C.h_in^T) ---------------
__global__ __launch_bounds__(256, 2) void k_ssd3(const unsigned short* __restrict__ xcb,
                                                 const float* __restrict__ dtf,
                                                 const float* __restrict__ alog,
                                                 const float* __restrict__ hst,
                                                 const float* __restrict__ Dw,
                                                 float* __restrict__ yb) {
    __shared__ bf16 Pl[4][64 * 72];
    __shared__ bf16 Xl[4][64 * 40];
    __shared__ bf16 Hl[4][64 * 36];
    __shared__ float ql[4][64];
    __shared__ float dl[4][64];
    const int bh = blockIdx.x >> 4, cg = blockIdx.x & 15;
    const int b = bh >> 3, h = bh & 7;
    const int wave = threadIdx.x >> 6, lane = threadIdx.x & 63;
    const int c = cg * 4 + wave;
    const size_t tok0 = (size_t)b * LSEQ + c * LC;
    const float A = -expf(alog[h]);
    const float Dh = Dw[h];
    float dt = dtf[(tok0 + lane) * NH + h];
    float q = dt * A * LOG2E;
    #pragma unroll
    for (int o = 1; o <= 32; o <<= 1) {
        float tmp = __shfl_up(q, o);
        if (lane >= o) q += tmp;
    }
    ql[wave][lane] = q;
    dl[wave][lane] = dt;
    const unsigned short* xrow = xcb + tok0 * CDIM;
    #pragma unroll
    for (int it = 0; it < 4; it++) {
        int f = it * 64 + lane, r = f >> 2, c8 = (f & 3) * 8;
        *(bf16x8*)&Xl[wave][r * 40 + c8] = *(const bf16x8*)(xrow + (size_t)r * CDIM + h * HD + c8);
    }
    const float* hbg = hst + (((size_t)bh * NC + c) << 11);
    #pragma unroll
    for (int it = 0; it < 8; it++) {
        int f = it * 64 + lane, r = f >> 3, c4 = (f & 7) * 4;
        float4 v = *(const float4*)(hbg + r * 32 + c4);
        bf16x4 o; o[0] = (bf16)v.x; o[1] = (bf16)v.y; o[2] = (bf16)v.z; o[3] = (bf16)v.w;
        *(bf16x4*)&Hl[wave][r * 36 + c4] = o;
    }
    const int m = lane & 15, ko = lane >> 4;
    // C frags (A-operand) direct bf16 loads
    bf16x8 cf[4][2];
    #pragma unroll
    for (int ti = 0; ti < 4; ti++)
        #pragma unroll
        for (int kh = 0; kh < 2; kh++)
            cf[ti][kh] = *(const bf16x8*)(xrow + (size_t)(ti * 16 + m) * CDIM + 320 + kh * 32 + ko * 8);
    // G = C.B^T
    f32x4 g[4][4] = {};
    #pragma unroll
    for (int kh = 0; kh < 2; kh++) {
        bf16x8 bfg[4];
        #pragma unroll
        for (int si = 0; si < 4; si++)
            bfg[si] = *(const bf16x8*)(xrow + (size_t)(si * 16 + m) * CDIM + 256 + kh * 32 + ko * 8);
        #pragma unroll
        for (int ti = 0; ti < 4; ti++)
            #pragma unroll
            for (int si = 0; si < 4; si++)
                g[ti][si] = __builtin_amdgcn_mfma_f32_16x16x32_bf16(cf[ti][kh], bfg[si], g[ti][si], 0, 0, 0);
    }
    __syncthreads();
    // P = G o W (+ D on diag), bf16 into LDS
    float qt[4][4], et[4][4];
    #pragma unroll
    for (int ti = 0; ti < 4; ti++)
        #pragma unroll
        for (int r = 0; r < 4; r++) {
            float v = ql[wave][ti * 16 + ko * 4 + r];
            qt[ti][r] = v; et[ti][r] = exp2f(v);
        }
    float qs[4], ds[4];
    #pragma unroll
    for (int si = 0; si < 4; si++) {
        qs[si] = ql[wave][si * 16 + m];
        ds[si] = dl[wave][si * 16 + m];
    }
    #pragma unroll
    for (int ti = 0; ti < 4; ti++)
        #pragma unroll
        for (int si = 0; si < 4; si++)
            #pragma unroll
            for (int r = 0; r < 4; r++) {
                int t = ti * 16 + ko * 4 + r, s = si * 16 + m;
                float p = 0.f;
                if (si <= ti) {
                    float w = (s <= t) ? exp2f(qt[ti][r] - qs[si]) * ds[si] : 0.f;
                    p = g[ti][si][r] * w;
                    if (s == t) p += Dh;
                }
                Pl[wave][t * 72 + s] = (bf16)p;
            }
    // Y = P.X + diag(et).(C.h_in^T)
    f32x4 ya[4][2] = {}, ua[4][2] = {};
    #pragma unroll
    for (int kh = 0; kh < 2; kh++) {
        bf16x8 xb[2], hb2[2];
        #pragma unroll
        for (int pi = 0; pi < 2; pi++)
            #pragma unroll
            for (int j = 0; j < 8; j++) {
                int kk = kh * 32 + ko * 8 + j;
                xb[pi][j]  = Xl[wave][kk * 40 + pi * 16 + m];
                hb2[pi][j] = Hl[wave][kk * 36 + pi * 16 + m];
            }
        #pragma unroll
        for (int ti = 0; ti < 4; ti++) {
            bf16x8 pa = *(const bf16x8*)&Pl[wave][(ti * 16 + m) * 72 + kh * 32 + ko * 8];
            #pragma unroll
            for (int pi = 0; pi < 2; pi++) {
                ya[ti][pi] = __builtin_amdgcn_mfma_f32_16x16x32_bf16(pa, xb[pi], ya[ti][pi], 0, 0, 0);
                ua[ti][pi] = __builtin_amdgcn_mfma_f32_16x16x32_bf16(cf[ti][kh], hb2[pi], ua[ti][pi], 0, 0, 0);
            }
        }
    }
    float* yrow = yb + tok0 * DI + h * HD;
    #pragma unroll
    for (int ti = 0; ti < 4; ti++)
        #pragma unroll
        for (int pi = 0; pi < 2; pi++)
            #pragma unroll
            for (int r = 0; r < 4; r++) {
                int t = ti * 16 + ko * 4 + r;
                yrow[(size_t)t * DI + pi * 16 + m] = ya[ti][pi][r] + et[ti][r] * ua[ti][pi][r];
            }
}

// ---------------- 6. gated RMSNorm -> bf16 -------------------------------------
__global__ __launch_bounds__(256) void k_gate(const float* __restrict__ yb,
                                              const unsigned short* __restrict__ zb,
                                              const float* __restrict__ gw,
                                              unsigned short* __restrict__ ynb) {
    int gid = blockIdx.x * 256 + threadIdx.x;
    int row = gid >> 6, lane = gid & 63;
    const float* yr = yb + (size_t)row * DI + lane * 4;
    float4 y = *(const float4*)yr;
    bf16x4 zv = *(const bf16x4*)(zb + (size_t)row * DI + lane * 4);
    float4 z; z.x = (float)zv[0]; z.y = (float)zv[1]; z.z = (float)zv[2]; z.w = (float)zv[3];
    float4 g;
    g.x = y.x * (z.x / (1.f + expf(-z.x)));
    g.y = y.y * (z.y / (1.f + expf(-z.y)));
    g.z = y.z * (z.z / (1.f + expf(-z.z)));
    g.w = y.w * (z.w / (1.f + expf(-z.w)));
    float ss = g.x * g.x + g.y * g.y + g.z * g.z + g.w * g.w;
    #pragma unroll
    for (int o = 32; o; o >>= 1) ss += __shfl_xor(ss, o);
    float r = rsqrtf(ss * (1.0f / DI) + EPSF);
    const float4 w = *(const float4*)(gw + lane * 4);
    ushort4 o;
    o.x = f2bfbits(g.x * r * w.x);
    o.y = f2bfbits(g.y * r * w.y);
    o.z = f2bfbits(g.z * r * w.z);
    o.w = f2bfbits(g.w * r * w.w);
    *(ushort4*)(ynb + (size_t)row * DI + lane * 4) = o;
}

// ---------------- 7. GEMM2 (bf16 MFMA) + residual ------------------------------
__global__ __launch_bounds__(256) void k_gemm2(const unsigned short* __restrict__ A,
                                               const unsigned short* __restrict__ B,
                                               const float* __restrict__ xin,
                                               float* __restrict__ out) {
    __shared__ bf16 As[64 * 40];
    __shared__ bf16 Bs[64 * 40];
    const int t = threadIdx.x;
    const int m0 = blockIdx.x * 64, n0 = blockIdx.y * 64;
    const int wave = t >> 6, lane = t & 63;
    const int wm = wave >> 1, wn = wave & 1;
    const int fr = lane & 15, fk = (lane >> 4) * 8;
    f32x4 acc[2][2] = {};
    const int r = t >> 2, q = (t & 3) * 8;
    for (int k0 = 0; k0 < DI; k0 += 32) {
        __syncthreads();
        *(short8*)&As[r * 40 + q] = *(const short8*)(A + (size_t)(m0 + r) * DI + k0 + q);
        *(short8*)&Bs[r * 40 + q] = *(const short8*)(B + (size_t)(n0 + r) * DI + k0 + q);
        __syncthreads();
        #pragma unroll
        for (int mt = 0; mt < 2; mt++) {
            bf16x8 af = *(const bf16x8*)&As[(wm * 32 + mt * 16 + fr) * 40 + fk];
            #pragma unroll
            for (int nt = 0; nt < 2; nt++) {
                bf16x8 bf = *(const bf16x8*)&Bs[(wn * 32 + nt * 16 + fr) * 40 + fk];
                acc[mt][nt] = __builtin_amdgcn_mfma_f32_16x16x32_bf16(af, bf, acc[mt][nt], 0, 0, 0);
            }
        }
    }
    #pragma unroll
    for (int mt = 0; mt < 2; mt++)
        #pragma unroll
        for (int nt = 0; nt < 2; nt++) {
            int n = n0 + wn * 32 + nt * 16 + fr;
            #pragma unroll
            for (int rr = 0; rr < 4; rr++) {
                int m = m0 + wm * 32 + mt * 16 + (lane >> 4) * 4 + rr;
                out[(size_t)m * DM + n] = xin[(size_t)m * DM + n] + acc[mt][nt][rr];
            }
        }
}

extern "C" void kernel_launch(void* const* d_in, const int* in_sizes, int n_in,
                              void* d_out, int out_size, void* d_ws, size_t ws_size,
                              hipStream_t stream) {
    const float* x   = (const float*)d_in[0];
    const float* nw  = (const float*)d_in[1];
    const float* w1  = (const float*)d_in[2];
    const float* cw  = (const float*)d_in[3];
    const float* cb  = (const float*)d_in[4];
    const float* dtb = (const float*)d_in[5];
    const float* al  = (const float*)d_in[6];
    const float* Dw  = (const float*)d_in[7];
    const float* gw  = (const float*)d_in[8];
    const float* w2  = (const float*)d_in[9];
    float* out = (float*)d_out;

    float* ws = (float*)d_ws;
    float*  yb  = ws;                                   // NTOK*256 fp32
    float*  hst = yb + (size_t)NTOK * DI;               // 64*64*2048 fp32
    float*  dAp = hst + (size_t)NB * NH * NC * 2048;    // 4096
    float*  dtf = dAp + NB * NH * NC;                   // NTOK*8 fp32
    unsigned short* zb  = (unsigned short*)(dtf + (size_t)NTOK * NH);  // NTOK*256 bf16
    unsigned short* xbc = zb + (size_t)NTOK * DI;                      // NTOK*384 bf16
    unsigned short* xcb = xbc + (size_t)NTOK * CDIM;                   // NTOK*384 bf16
    unsigned short* w1b = xcb + (size_t)NTOK * CDIM;                   // 648*128
    unsigned short* w2b = w1b + (size_t)DPROJ * DM;                    // 128*256
    // aliases (lifetimes disjoint):
    float*          xnf = hst;                 // dead before ssd1 writes hst
    unsigned short* xnb = (unsigned short*)yb; // dead before ssd3 writes yb
    unsigned short* ynb = xbc;                 // xbc dead after conv

    k_cast<<<(DPROJ * DM + 255) / 256, 256, 0, stream>>>(w1, w1b, DPROJ * DM);
    k_cast<<<(DM * DI + 255) / 256, 256, 0, stream>>>(w2, w2b, DM * DI);
    k_rmsnorm<<<NTOK / 4, 256, 0, stream>>>(x, nw, xnf, xnb);
    k_gemm1<<<dim3(NTOK / 64, (DPROJ + 63) / 64), 256, 0, stream>>>(xnb, w1b, zb, xbc);
    k_conv<<<NTOK / 64, 384, 0, stream>>>(xbc, cw, cb, xcb);
    k_dt<<<NTOK / 4, 256, 0, stream>>>(xnf, w1, dtb, dtf);
    k_ssd1<<<NB * NH * (NC / 4), 256, 0, stream>>>(xcb, dtf, al, hst, dAp);
    k_ssm2<<<NB * NH * 8, 256, 0, stream>>>(hst, dAp);
    k_ssd3<<<NB * NH * (NC / 4), 256, 0, stream>>>(xcb, dtf, al, hst, Dw, yb);
    k_gate<<<NTOK / 4, 256, 0, stream>>>(yb, zb, gw, ynb);
    k_gemm2<<<dim3(NTOK / 64, DM / 64), 256, 0, stream>>>(ynb, w2b, x, out);
}

// Round 7
// 205.767 us; speedup vs baseline: 16.3965x; 1.2150x over previous
//
#include <hip/hip_runtime.h>

#define DM    128
#define DI    256
#define NH    8
#define HD    32
#define NS    64
#define CDIM  384
#define DPROJ 648
#define LSEQ  4096
#define NB    8
#define NTOK  32768          // NB*LSEQ
#define LC    64             // chunk length
#define NC    64             // chunks per (b,h) sequence
#define EPSF  1e-5f
#define LOG2E 1.4426950408889634f

typedef __bf16 bf16;
typedef bf16  bf16x8 __attribute__((ext_vector_type(8)));
typedef bf16  bf16x4 __attribute__((ext_vector_type(4)));
typedef short short8 __attribute__((ext_vector_type(8)));
typedef float f32x4  __attribute__((ext_vector_type(4)));

__device__ __forceinline__ unsigned short f2bfbits(float f) {
    unsigned int u = __float_as_uint(f);
    unsigned int r = u + 0x7FFFu + ((u >> 16) & 1u);   // RNE
    return (unsigned short)(r >> 16);
}
__device__ __forceinline__ float bfbits2f(unsigned short u) {
    return __uint_as_float(((unsigned int)u) << 16);
}

// ---------------- 0. fp32 -> bf16 weight cast ----------------------------------
__global__ __launch_bounds__(256) void k_cast(const float* __restrict__ in,
                                              unsigned short* __restrict__ out, int n) {
    int i = blockIdx.x * 256 + threadIdx.x;
    if (i < n) out[i] = f2bfbits(in[i]);
}

// ---------------- 1. input RMSNorm: xn (fp32 + bf16 copies) --------------------
__global__ __launch_bounds__(256) void k_rmsnorm(const float* __restrict__ x,
                                                 const float* __restrict__ w,
                                                 float* __restrict__ xnf,
                                                 unsigned short* __restrict__ xnb) {
    int gid = blockIdx.x * 256 + threadIdx.x;
    int row = gid >> 6, lane = gid & 63;
    const float* xr = x + (size_t)row * DM + lane * 2;
    float v0 = xr[0], v1 = xr[1];
    float ss = v0 * v0 + v1 * v1;
    #pragma unroll
    for (int o = 32; o; o >>= 1) ss += __shfl_xor(ss, o);
    float r = rsqrtf(ss * (1.0f / DM) + EPSF);
    float o0 = v0 * r * w[lane * 2], o1 = v1 * r * w[lane * 2 + 1];
    float* of = xnf + (size_t)row * DM + lane * 2;
    of[0] = o0; of[1] = o1;
    ushort2 ob; ob.x = f2bfbits(o0); ob.y = f2bfbits(o1);
    *(ushort2*)(xnb + (size_t)row * DM + lane * 2) = ob;
}

// ---------------- 2. GEMM1 (bf16 MFMA): split bf16 out (z | xBC) ---------------
__global__ __launch_bounds__(256) void k_gemm1(const unsigned short* __restrict__ A,
                                               const unsigned short* __restrict__ B,
                                               unsigned short* __restrict__ zb,
                                               unsigned short* __restrict__ xbc) {
    __shared__ bf16 As[64 * 40];
    __shared__ bf16 Bs[64 * 40];
    const int t = threadIdx.x;
    const int m0 = blockIdx.x * 64, n0 = blockIdx.y * 64;
    const int wave = t >> 6, lane = t & 63;
    const int wm = wave >> 1, wn = wave & 1;
    const int fr = lane & 15, fk = (lane >> 4) * 8;
    f32x4 acc[2][2] = {};
    const int r = t >> 2, q = (t & 3) * 8;
    for (int k0 = 0; k0 < DM; k0 += 32) {
        __syncthreads();
        *(short8*)&As[r * 40 + q] = *(const short8*)(A + (size_t)(m0 + r) * DM + k0 + q);
        short8 bv = {};
        if (n0 + r < DPROJ) bv = *(const short8*)(B + (size_t)(n0 + r) * DM + k0 + q);
        *(short8*)&Bs[r * 40 + q] = bv;
        __syncthreads();
        #pragma unroll
        for (int mt = 0; mt < 2; mt++) {
            bf16x8 af = *(const bf16x8*)&As[(wm * 32 + mt * 16 + fr) * 40 + fk];
            #pragma unroll
            for (int nt = 0; nt < 2; nt++) {
                bf16x8 bf = *(const bf16x8*)&Bs[(wn * 32 + nt * 16 + fr) * 40 + fk];
                acc[mt][nt] = __builtin_amdgcn_mfma_f32_16x16x32_bf16(af, bf, acc[mt][nt], 0, 0, 0);
            }
        }
    }
    #pragma unroll
    for (int mt = 0; mt < 2; mt++)
        #pragma unroll
        for (int nt = 0; nt < 2; nt++) {
            int n = n0 + wn * 32 + nt * 16 + fr;
            if (n >= 640) continue;
            #pragma unroll
            for (int rr = 0; rr < 4; rr++) {
                int m = m0 + wm * 32 + mt * 16 + (lane >> 4) * 4 + rr;
                unsigned short v = f2bfbits(acc[mt][nt][rr]);
                if (n < DI) zb[(size_t)m * DI + n] = v;
                else        xbc[(size_t)m * CDIM + (n - 256)] = v;
            }
        }
}

// ---------------- 3. causal depthwise conv (K=4) + SiLU, bf16 ------------------
__global__ __launch_bounds__(384) void k_conv(const unsigned short* __restrict__ xbc,
                                              const float* __restrict__ cw,
                                              const float* __restrict__ cb,
                                              unsigned short* __restrict__ xcb) {
    const int c = threadIdx.x;
    const int t0 = blockIdx.x * 64;
    const int l0 = t0 & (LSEQ - 1);
    float4 wv = *(const float4*)(cw + c * 4);
    float bias = cb[c];
    const unsigned short* in = xbc + (size_t)t0 * CDIM + c;
    unsigned short* out = xcb + (size_t)t0 * CDIM + c;
    float h1 = 0.f, h2 = 0.f, h3 = 0.f;
    if (l0) {
        h1 = bfbits2f(in[-CDIM]);
        h2 = bfbits2f(in[-2 * CDIM]);
        h3 = bfbits2f(in[-3 * CDIM]);
    }
    #pragma unroll 4
    for (int t = 0; t < 64; t++) {
        float x0 = bfbits2f(in[(size_t)t * CDIM]);
        float acc = bias;
        acc = fmaf(x0, wv.w, acc);
        acc = fmaf(h1, wv.z, acc);
        acc = fmaf(h2, wv.y, acc);
        acc = fmaf(h3, wv.x, acc);
        float s = acc / (1.f + expf(-acc));
        out[(size_t)t * CDIM] = f2bfbits(s);
        h3 = h2; h2 = h1; h1 = x0;
    }
}

// ---------------- 4. dt prep (fp32 path): per-thread dot, no shuffles ----------
// block = 256 threads = 32 tokens x 8 heads; xn rows + W1d staged in LDS
__global__ __launch_bounds__(256) void k_dt(const float* __restrict__ xnf,
                                            const float* __restrict__ w1,
                                            const float* __restrict__ dtb,
                                            float* __restrict__ dtf) {
    __shared__ float Xl[32][132];
    __shared__ float Wd[8][132];
    const int t = threadIdx.x;
    {
        int row = t >> 5, col = (t & 31) * 4;           // 256 float4 = 8x128
        float4 v = *(const float4*)(w1 + (size_t)(640 + row) * DM + col);
        *(float4*)&Wd[row][col] = v;
    }
    const size_t tok0 = (size_t)blockIdx.x * 32;
    #pragma unroll
    for (int i = 0; i < 4; i++) {
        int idx = i * 256 + t;                          // 1024 float4 = 32x128
        int row = idx >> 5, col = (idx & 31) * 4;
        float4 v = *(const float4*)(xnf + (tok0 + row) * DM + col);
        *(float4*)&Xl[row][col] = v;
    }
    __syncthreads();
    const int tok = t >> 3, h = t & 7;
    float acc = 0.f;
    #pragma unroll
    for (int k = 0; k < DM; k += 4) {
        float4 xv = *(const float4*)&Xl[tok][k];
        float4 wv = *(const float4*)&Wd[h][k];
        acc = fmaf(xv.x, wv.x, acc);
        acc = fmaf(xv.y, wv.y, acc);
        acc = fmaf(xv.z, wv.z, acc);
        acc = fmaf(xv.w, wv.w, acc);
    }
    float v = acc + dtb[h];
    dtf[(tok0 + tok) * NH + h] = (v > 20.f) ? v : log1pf(expf(v));
}

// ---------------- 5a. SSD pass 1: chunk-local end state via MFMA ---------------
__global__ __launch_bounds__(256, 2) void k_ssd1(const unsigned short* __restrict__ xcb,
                                                 const float* __restrict__ dtf,
                                                 const float* __restrict__ alog,
                                                 float* __restrict__ hst,
                                                 float* __restrict__ dAp) {
    __shared__ bf16 Wl[4][64 * 72];
    __shared__ bf16 Xl[4][64 * 40];
    __shared__ float wl[4][64];
    const int bh = blockIdx.x >> 4, cg = blockIdx.x & 15;
    const int b = bh >> 3, h = bh & 7;
    const int wave = threadIdx.x >> 6, lane = threadIdx.x & 63;
    const int c = cg * 4 + wave;
    const size_t tok0 = (size_t)b * LSEQ + c * LC;
    const float A = -expf(alog[h]);
    float dt = dtf[(tok0 + lane) * NH + h];
    float q = dt * A * LOG2E;
    #pragma unroll
    for (int o = 1; o <= 32; o <<= 1) {
        float tmp = __shfl_up(q, o);
        if (lane >= o) q += tmp;
    }
    float qL = __shfl(q, 63);
    wl[wave][lane] = exp2f(qL - q) * dt;
    const unsigned short* xrow = xcb + tok0 * CDIM;
    #pragma unroll
    for (int it = 0; it < 4; it++) {
        int f = it * 64 + lane, r = f >> 2, c8 = (f & 3) * 8;
        *(bf16x8*)&Xl[wave][r * 40 + c8] = *(const bf16x8*)(xrow + (size_t)r * CDIM + h * HD + c8);
    }
    #pragma unroll
    for (int it = 0; it < 8; it++) {
        int f = it * 64 + lane, r = f >> 3, c8 = (f & 7) * 8;
        float w = wl[wave][r];
        bf16x8 v = *(const bf16x8*)(xrow + (size_t)r * CDIM + 256 + c8);
        bf16x8 o;
        #pragma unroll
        for (int j = 0; j < 8; j++) o[j] = (bf16)((float)v[j] * w);
        *(bf16x8*)&Wl[wave][r * 72 + c8] = o;
    }
    const int m = lane & 15, ko = lane >> 4;
    f32x4 hacc[4][2] = {};
    #pragma unroll
    for (int kh = 0; kh < 2; kh++) {
        bf16x8 xb[2];
        #pragma unroll
        for (int pi = 0; pi < 2; pi++)
            #pragma unroll
            for (int j = 0; j < 8; j++)
                xb[pi][j] = Xl[wave][(kh * 32 + ko * 8 + j) * 40 + pi * 16 + m];
        #pragma unroll
        for (int ni = 0; ni < 4; ni++) {
            bf16x8 af;
            #pragma unroll
            for (int j = 0; j < 8; j++)
                af[j] = Wl[wave][(kh * 32 + ko * 8 + j) * 72 + ni * 16 + m];
            #pragma unroll
            for (int pi = 0; pi < 2; pi++)
                hacc[ni][pi] = __builtin_amdgcn_mfma_f32_16x16x32_bf16(af, xb[pi], hacc[ni][pi], 0, 0, 0);
        }
    }
    float* hb = hst + (((size_t)bh * NC + c) << 11);
    #pragma unroll
    for (int ni = 0; ni < 4; ni++)
        #pragma unroll
        for (int pi = 0; pi < 2; pi++)
            #pragma unroll
            for (int r = 0; r < 4; r++)
                hb[(ni * 16 + ko * 4 + r) * 32 + pi * 16 + m] = hacc[ni][pi][r];
    if (lane == 0) dAp[(size_t)bh * NC + c] = exp2f(qL);
}

// ---------------- 5b. SSM pass 2: exclusive scan over chunk states -------------
__global__ __launch_bounds__(256) void k_ssm2(float* __restrict__ hst,
                                              const float* __restrict__ dAp) {
    const int bh = blockIdx.x >> 3, seg = blockIdx.x & 7;
    const int s = seg * 256 + threadIdx.x;
    float* base = hst + ((size_t)bh * NC << 11) + s;
    const float* dap = dAp + (size_t)bh * NC;
    float run = 0.f;
    for (int c = 0; c < NC; c++) {
        float tmp = base[(size_t)c << 11];
        base[(size_t)c << 11] = run;
        run = fmaf(run, dap[c], tmp);
    }
}

// ---------------- 5c. SSD pass 3: Y = P.X + diag(2^q).(C.h_in^T) ---------------
__global__ __launch_bounds__(256, 2) void k_ssd3(const unsigned short* __restrict__ xcb,
                                                 const float* __restrict__ dtf,
                                                 const float* __restrict__ alog,
                                                 const float* __restrict__ hst,
                                                 const float* __restrict__ Dw,
                                                 float* __restrict__ yb) {
    __shared__ bf16 Pl[4][64 * 72];
    __shared__ bf16 Xl[4][64 * 40];
    __shared__ bf16 Hl[4][64 * 36];
    __shared__ float ql[4][64];
    __shared__ float dl[4][64];
    const int bh = blockIdx.x >> 4, cg = blockIdx.x & 15;
    const int b = bh >> 3, h = bh & 7;
    const int wave = threadIdx.x >> 6, lane = threadIdx.x & 63;
    const int c = cg * 4 + wave;
    const size_t tok0 = (size_t)b * LSEQ + c * LC;
    const float A = -expf(alog[h]);
    const float Dh = Dw[h];
    float dt = dtf[(tok0 + lane) * NH + h];
    float q = dt * A * LOG2E;
    #pragma unroll
    for (int o = 1; o <= 32; o <<= 1) {
        float tmp = __shfl_up(q, o);
        if (lane >= o) q += tmp;
    }
    ql[wave][lane] = q;
    dl[wave][lane] = dt;
    const unsigned short* xrow = xcb + tok0 * CDIM;
    #pragma unroll
    for (int it = 0; it < 4; it++) {
        int f = it * 64 + lane, r = f >> 2, c8 = (f & 3) * 8;
        *(bf16x8*)&Xl[wave][r * 40 + c8] = *(const bf16x8*)(xrow + (size_t)r * CDIM + h * HD + c8);
    }
    const float* hbg = hst + (((size_t)bh * NC + c) << 11);
    #pragma unroll
    for (int it = 0; it < 8; it++) {
        int f = it * 64 + lane, r = f >> 3, c4 = (f & 7) * 4;
        float4 v = *(const float4*)(hbg + r * 32 + c4);
        bf16x4 o; o[0] = (bf16)v.x; o[1] = (bf16)v.y; o[2] = (bf16)v.z; o[3] = (bf16)v.w;
        *(bf16x4*)&Hl[wave][r * 36 + c4] = o;
    }
    const int m = lane & 15, ko = lane >> 4;
    bf16x8 cf[4][2];
    #pragma unroll
    for (int ti = 0; ti < 4; ti++)
        #pragma unroll
        for (int kh = 0; kh < 2; kh++)
            cf[ti][kh] = *(const bf16x8*)(xrow + (size_t)(ti * 16 + m) * CDIM + 320 + kh * 32 + ko * 8);
    f32x4 g[4][4] = {};
    #pragma unroll
    for (int kh = 0; kh < 2; kh++) {
        bf16x8 bfg[4];
        #pragma unroll
        for (int si = 0; si < 4; si++)
            bfg[si] = *(const bf16x8*)(xrow + (size_t)(si * 16 + m) * CDIM + 256 + kh * 32 + ko * 8);
        #pragma unroll
        for (int ti = 0; ti < 4; ti++)
            #pragma unroll
            for (int si = 0; si < 4; si++)
                g[ti][si] = __builtin_amdgcn_mfma_f32_16x16x32_bf16(cf[ti][kh], bfg[si], g[ti][si], 0, 0, 0);
    }
    __syncthreads();
    float qt[4][4], et[4][4];
    #pragma unroll
    for (int ti = 0; ti < 4; ti++)
        #pragma unroll
        for (int r = 0; r < 4; r++) {
            float v = ql[wave][ti * 16 + ko * 4 + r];
            qt[ti][r] = v; et[ti][r] = exp2f(v);
        }
    float qs[4], ds[4];
    #pragma unroll
    for (int si = 0; si < 4; si++) {
        qs[si] = ql[wave][si * 16 + m];
        ds[si] = dl[wave][si * 16 + m];
    }
    #pragma unroll
    for (int ti = 0; ti < 4; ti++)
        #pragma unroll
        for (int si = 0; si < 4; si++)
            #pragma unroll
            for (int r = 0; r < 4; r++) {
                int t = ti * 16 + ko * 4 + r, s = si * 16 + m;
                float p = 0.f;
                if (si <= ti) {
                    float w = (s <= t) ? exp2f(qt[ti][r] - qs[si]) * ds[si] : 0.f;
                    p = g[ti][si][r] * w;
                    if (s == t) p += Dh;
                }
                Pl[wave][t * 72 + s] = (bf16)p;
            }
    f32x4 ya[4][2] = {}, ua[4][2] = {};
    #pragma unroll
    for (int kh = 0; kh < 2; kh++) {
        bf16x8 xb[2], hb2[2];
        #pragma unroll
        for (int pi = 0; pi < 2; pi++)
            #pragma unroll
            for (int j = 0; j < 8; j++) {
                int kk = kh * 32 + ko * 8 + j;
                xb[pi][j]  = Xl[wave][kk * 40 + pi * 16 + m];
                hb2[pi][j] = Hl[wave][kk * 36 + pi * 16 + m];
            }
        #pragma unroll
        for (int ti = 0; ti < 4; ti++) {
            bf16x8 pa = *(const bf16x8*)&Pl[wave][(ti * 16 + m) * 72 + kh * 32 + ko * 8];
            #pragma unroll
            for (int pi = 0; pi < 2; pi++) {
                ya[ti][pi] = __builtin_amdgcn_mfma_f32_16x16x32_bf16(pa, xb[pi], ya[ti][pi], 0, 0, 0);
                ua[ti][pi] = __builtin_amdgcn_mfma_f32_16x16x32_bf16(cf[ti][kh], hb2[pi], ua[ti][pi], 0, 0, 0);
            }
        }
    }
    float* yrow = yb + tok0 * DI + h * HD;
    #pragma unroll
    for (int ti = 0; ti < 4; ti++)
        #pragma unroll
        for (int pi = 0; pi < 2; pi++)
            #pragma unroll
            for (int r = 0; r < 4; r++) {
                int t = ti * 16 + ko * 4 + r;
                yrow[(size_t)t * DI + pi * 16 + m] = ya[ti][pi][r] + et[ti][r] * ua[ti][pi][r];
            }
}

// ---------------- 6. gated RMSNorm -> bf16 -------------------------------------
__global__ __launch_bounds__(256) void k_gate(const float* __restrict__ yb,
                                              const unsigned short* __restrict__ zb,
                                              const float* __restrict__ gw,
                                              unsigned short* __restrict__ ynb) {
    int gid = blockIdx.x * 256 + threadIdx.x;
    int row = gid >> 6, lane = gid & 63;
    const float* yr = yb + (size_t)row * DI + lane * 4;
    float4 y = *(const float4*)yr;
    bf16x4 zv = *(const bf16x4*)(zb + (size_t)row * DI + lane * 4);
    float4 z; z.x = (float)zv[0]; z.y = (float)zv[1]; z.z = (float)zv[2]; z.w = (float)zv[3];
    float4 g;
    g.x = y.x * (z.x / (1.f + expf(-z.x)));
    g.y = y.y * (z.y / (1.f + expf(-z.y)));
    g.z = y.z * (z.z / (1.f + expf(-z.z)));
    g.w = y.w * (z.w / (1.f + expf(-z.w)));
    float ss = g.x * g.x + g.y * g.y + g.z * g.z + g.w * g.w;
    #pragma unroll
    for (int o = 32; o; o >>= 1) ss += __shfl_xor(ss, o);
    float r = rsqrtf(ss * (1.0f / DI) + EPSF);
    const float4 w = *(const float4*)(gw + lane * 4);
    ushort4 o;
    o.x = f2bfbits(g.x * r * w.x);
    o.y = f2bfbits(g.y * r * w.y);
    o.z = f2bfbits(g.z * r * w.z);
    o.w = f2bfbits(g.w * r * w.w);
    *(ushort4*)(ynb + (size_t)row * DI + lane * 4) = o;
}

// ---------------- 7. GEMM2 (bf16 MFMA) + residual ------------------------------
__global__ __launch_bounds__(256) void k_gemm2(const unsigned short* __restrict__ A,
                                               const unsigned short* __restrict__ B,
                                               const float* __restrict__ xin,
                                               float* __restrict__ out) {
    __shared__ bf16 As[64 * 40];
    __shared__ bf16 Bs[64 * 40];
    const int t = threadIdx.x;
    const int m0 = blockIdx.x * 64, n0 = blockIdx.y * 64;
    const int wave = t >> 6, lane = t & 63;
    const int wm = wave >> 1, wn = wave & 1;
    const int fr = lane & 15, fk = (lane >> 4) * 8;
    f32x4 acc[2][2] = {};
    const int r = t >> 2, q = (t & 3) * 8;
    for (int k0 = 0; k0 < DI; k0 += 32) {
        __syncthreads();
        *(short8*)&As[r * 40 + q] = *(const short8*)(A + (size_t)(m0 + r) * DI + k0 + q);
        *(short8*)&Bs[r * 40 + q] = *(const short8*)(B + (size_t)(n0 + r) * DI + k0 + q);
        __syncthreads();
        #pragma unroll
        for (int mt = 0; mt < 2; mt++) {
            bf16x8 af = *(const bf16x8*)&As[(wm * 32 + mt * 16 + fr) * 40 + fk];
            #pragma unroll
            for (int nt = 0; nt < 2; nt++) {
                bf16x8 bf = *(const bf16x8*)&Bs[(wn * 32 + nt * 16 + fr) * 40 + fk];
                acc[mt][nt] = __builtin_amdgcn_mfma_f32_16x16x32_bf16(af, bf, acc[mt][nt], 0, 0, 0);
            }
        }
    }
    #pragma unroll
    for (int mt = 0; mt < 2; mt++)
        #pragma unroll
        for (int nt = 0; nt < 2; nt++) {
            int n = n0 + wn * 32 + nt * 16 + fr;
            #pragma unroll
            for (int rr = 0; rr < 4; rr++) {
                int m = m0 + wm * 32 + mt * 16 + (lane >> 4) * 4 + rr;
                out[(size_t)m * DM + n] = xin[(size_t)m * DM + n] + acc[mt][nt][rr];
            }
        }
}

extern "C" void kernel_launch(void* const* d_in, const int* in_sizes, int n_in,
                              void* d_out, int out_size, void* d_ws, size_t ws_size,
                              hipStream_t stream) {
    const float* x   = (const float*)d_in[0];
    const float* nw  = (const float*)d_in[1];
    const float* w1  = (const float*)d_in[2];
    const float* cw  = (const float*)d_in[3];
    const float* cb  = (const float*)d_in[4];
    const float* dtb = (const float*)d_in[5];
    const float* al  = (const float*)d_in[6];
    const float* Dw  = (const float*)d_in[7];
    const float* gw  = (const float*)d_in[8];
    const float* w2  = (const float*)d_in[9];
    float* out = (float*)d_out;

    float* ws = (float*)d_ws;
    float*  yb  = ws;                                   // NTOK*256 fp32
    float*  hst = yb + (size_t)NTOK * DI;               // 64*64*2048 fp32
    float*  dAp = hst + (size_t)NB * NH * NC * 2048;    // 4096
    float*  dtf = dAp + NB * NH * NC;                   // NTOK*8 fp32
    unsigned short* zb  = (unsigned short*)(dtf + (size_t)NTOK * NH);  // NTOK*256 bf16
    unsigned short* xbc = zb + (size_t)NTOK * DI;                      // NTOK*384 bf16
    unsigned short* xcb = xbc + (size_t)NTOK * CDIM;                   // NTOK*384 bf16
    unsigned short* w1b = xcb + (size_t)NTOK * CDIM;                   // 648*128
    unsigned short* w2b = w1b + (size_t)DPROJ * DM;                    // 128*256
    // aliases (lifetimes disjoint):
    float*          xnf = hst;                 // dead before ssd1 writes hst
    unsigned short* xnb = (unsigned short*)yb; // dead before ssd3 writes yb
    unsigned short* ynb = xbc;                 // xbc dead after conv

    k_cast<<<(DPROJ * DM + 255) / 256, 256, 0, stream>>>(w1, w1b, DPROJ * DM);
    k_cast<<<(DM * DI + 255) / 256, 256, 0, stream>>>(w2, w2b, DM * DI);
    k_rmsnorm<<<NTOK / 4, 256, 0, stream>>>(x, nw, xnf, xnb);
    k_gemm1<<<dim3(NTOK / 64, (DPROJ + 63) / 64), 256, 0, stream>>>(xnb, w1b, zb, xbc);
    k_conv<<<NTOK / 64, 384, 0, stream>>>(xbc, cw, cb, xcb);
    k_dt<<<NTOK / 32, 256, 0, stream>>>(xnf, w1, dtb, dtf);
    k_ssd1<<<NB * NH * (NC / 4), 256, 0, stream>>>(xcb, dtf, al, hst, dAp);
    k_ssm2<<<NB * NH * 8, 256, 0, stream>>>(hst, dAp);
    k_ssd3<<<NB * NH * (NC / 4), 256, 0, stream>>>(xcb, dtf, al, hst, Dw, yb);
    k_gate<<<NTOK / 4, 256, 0, stream>>>(yb, zb, gw, ynb);
    k_gemm2<<<dim3(NTOK / 64, DM / 64), 256, 0, stream>>>(ynb, w2b, x, out);
}

// Round 8
// 201.728 us; speedup vs baseline: 16.7248x; 1.0200x over previous
//
#include <hip/hip_runtime.h>

#define DM    128
#define DI    256
#define NH    8
#define HD    32
#define NS    64
#define CDIM  384
#define DPROJ 648
#define LSEQ  4096
#define NB    8
#define NTOK  32768          // NB*LSEQ
#define LC    64             // chunk length
#define NC    64             // chunks per (b,h) sequence
#define EPSF  1e-5f
#define LOG2E 1.4426950408889634f

typedef __bf16 bf16;
typedef bf16  bf16x8 __attribute__((ext_vector_type(8)));
typedef bf16  bf16x4 __attribute__((ext_vector_type(4)));
typedef short short8 __attribute__((ext_vector_type(8)));
typedef float f32x4  __attribute__((ext_vector_type(4)));

__device__ __forceinline__ unsigned short f2bfbits(float f) {
    unsigned int u = __float_as_uint(f);
    unsigned int r = u + 0x7FFFu + ((u >> 16) & 1u);   // RNE
    return (unsigned short)(r >> 16);
}
__device__ __forceinline__ float bfbits2f(unsigned short u) {
    return __uint_as_float(((unsigned int)u) << 16);
}

// ---------------- 0. fp32 -> bf16 weight cast ----------------------------------
__global__ __launch_bounds__(256) void k_cast(const float* __restrict__ in,
                                              unsigned short* __restrict__ out, int n) {
    int i = blockIdx.x * 256 + threadIdx.x;
    if (i < n) out[i] = f2bfbits(in[i]);
}

// ---------------- 1. input RMSNorm: xn (fp32 + bf16 copies) --------------------
__global__ __launch_bounds__(256) void k_rmsnorm(const float* __restrict__ x,
                                                 const float* __restrict__ w,
                                                 float* __restrict__ xnf,
                                                 unsigned short* __restrict__ xnb) {
    int gid = blockIdx.x * 256 + threadIdx.x;
    int row = gid >> 6, lane = gid & 63;
    const float* xr = x + (size_t)row * DM + lane * 2;
    float v0 = xr[0], v1 = xr[1];
    float ss = v0 * v0 + v1 * v1;
    #pragma unroll
    for (int o = 32; o; o >>= 1) ss += __shfl_xor(ss, o);
    float r = rsqrtf(ss * (1.0f / DM) + EPSF);
    float o0 = v0 * r * w[lane * 2], o1 = v1 * r * w[lane * 2 + 1];
    float* of = xnf + (size_t)row * DM + lane * 2;
    of[0] = o0; of[1] = o1;
    ushort2 ob; ob.x = f2bfbits(o0); ob.y = f2bfbits(o1);
    *(ushort2*)(xnb + (size_t)row * DM + lane * 2) = ob;
}

// ---------------- 2. GEMM1 (bf16 MFMA): split bf16 out (z | xBC) ---------------
__global__ __launch_bounds__(256) void k_gemm1(const unsigned short* __restrict__ A,
                                               const unsigned short* __restrict__ B,
                                               unsigned short* __restrict__ zb,
                                               unsigned short* __restrict__ xbc) {
    __shared__ bf16 As[64 * 40];
    __shared__ bf16 Bs[64 * 40];
    const int t = threadIdx.x;
    const int m0 = blockIdx.x * 64, n0 = blockIdx.y * 64;
    const int wave = t >> 6, lane = t & 63;
    const int wm = wave >> 1, wn = wave & 1;
    const int fr = lane & 15, fk = (lane >> 4) * 8;
    f32x4 acc[2][2] = {};
    const int r = t >> 2, q = (t & 3) * 8;
    for (int k0 = 0; k0 < DM; k0 += 32) {
        __syncthreads();
        *(short8*)&As[r * 40 + q] = *(const short8*)(A + (size_t)(m0 + r) * DM + k0 + q);
        short8 bv = {};
        if (n0 + r < DPROJ) bv = *(const short8*)(B + (size_t)(n0 + r) * DM + k0 + q);
        *(short8*)&Bs[r * 40 + q] = bv;
        __syncthreads();
        #pragma unroll
        for (int mt = 0; mt < 2; mt++) {
            bf16x8 af = *(const bf16x8*)&As[(wm * 32 + mt * 16 + fr) * 40 + fk];
            #pragma unroll
            for (int nt = 0; nt < 2; nt++) {
                bf16x8 bf = *(const bf16x8*)&Bs[(wn * 32 + nt * 16 + fr) * 40 + fk];
                acc[mt][nt] = __builtin_amdgcn_mfma_f32_16x16x32_bf16(af, bf, acc[mt][nt], 0, 0, 0);
            }
        }
    }
    #pragma unroll
    for (int mt = 0; mt < 2; mt++)
        #pragma unroll
        for (int nt = 0; nt < 2; nt++) {
            int n = n0 + wn * 32 + nt * 16 + fr;
            if (n >= 640) continue;
            #pragma unroll
            for (int rr = 0; rr < 4; rr++) {
                int m = m0 + wm * 32 + mt * 16 + (lane >> 4) * 4 + rr;
                unsigned short v = f2bfbits(acc[mt][nt][rr]);
                if (n < DI) zb[(size_t)m * DI + n] = v;
                else        xbc[(size_t)m * CDIM + (n - 256)] = v;
            }
        }
}

// ---------------- 3. causal depthwise conv (K=4) + SiLU, bf16 ------------------
__global__ __launch_bounds__(384) void k_conv(const unsigned short* __restrict__ xbc,
                                              const float* __restrict__ cw,
                                              const float* __restrict__ cb,
                                              unsigned short* __restrict__ xcb) {
    const int c = threadIdx.x;
    const int t0 = blockIdx.x * 64;
    const int l0 = t0 & (LSEQ - 1);
    float4 wv = *(const float4*)(cw + c * 4);
    float bias = cb[c];
    const unsigned short* in = xbc + (size_t)t0 * CDIM + c;
    unsigned short* out = xcb + (size_t)t0 * CDIM + c;
    float h1 = 0.f, h2 = 0.f, h3 = 0.f;
    if (l0) {
        h1 = bfbits2f(in[-CDIM]);
        h2 = bfbits2f(in[-2 * CDIM]);
        h3 = bfbits2f(in[-3 * CDIM]);
    }
    #pragma unroll 4
    for (int t = 0; t < 64; t++) {
        float x0 = bfbits2f(in[(size_t)t * CDIM]);
        float acc = bias;
        acc = fmaf(x0, wv.w, acc);
        acc = fmaf(h1, wv.z, acc);
        acc = fmaf(h2, wv.y, acc);
        acc = fmaf(h3, wv.x, acc);
        float s = acc / (1.f + expf(-acc));
        out[(size_t)t * CDIM] = f2bfbits(s);
        h3 = h2; h2 = h1; h1 = x0;
    }
}

// ---------------- 4. dt prep (fp32 path): per-thread dot, no shuffles ----------
__global__ __launch_bounds__(256) void k_dt(const float* __restrict__ xnf,
                                            const float* __restrict__ w1,
                                            const float* __restrict__ dtb,
                                            float* __restrict__ dtf) {
    __shared__ float Xl[32][132];
    __shared__ float Wd[8][132];
    const int t = threadIdx.x;
    {
        int row = t >> 5, col = (t & 31) * 4;
        float4 v = *(const float4*)(w1 + (size_t)(640 + row) * DM + col);
        *(float4*)&Wd[row][col] = v;
    }
    const size_t tok0 = (size_t)blockIdx.x * 32;
    #pragma unroll
    for (int i = 0; i < 4; i++) {
        int idx = i * 256 + t;
        int row = idx >> 5, col = (idx & 31) * 4;
        float4 v = *(const float4*)(xnf + (tok0 + row) * DM + col);
        *(float4*)&Xl[row][col] = v;
    }
    __syncthreads();
    const int tok = t >> 3, h = t & 7;
    float acc = 0.f;
    #pragma unroll
    for (int k = 0; k < DM; k += 4) {
        float4 xv = *(const float4*)&Xl[tok][k];
        float4 wv = *(const float4*)&Wd[h][k];
        acc = fmaf(xv.x, wv.x, acc);
        acc = fmaf(xv.y, wv.y, acc);
        acc = fmaf(xv.z, wv.z, acc);
        acc = fmaf(xv.w, wv.w, acc);
    }
    float v = acc + dtb[h];
    dtf[(tok0 + tok) * NH + h] = (v > 20.f) ? v : log1pf(expf(v));
}

// ---------------- 5a. SSD pass 1: chunk-local end state via MFMA ---------------
__global__ __launch_bounds__(256, 2) void k_ssd1(const unsigned short* __restrict__ xcb,
                                                 const float* __restrict__ dtf,
                                                 const float* __restrict__ alog,
                                                 float* __restrict__ hst,
                                                 float* __restrict__ dAp) {
    __shared__ bf16 Wl[4][64 * 72];
    __shared__ bf16 Xl[4][64 * 40];
    __shared__ float wl[4][64];
    const int bh = blockIdx.x >> 4, cg = blockIdx.x & 15;
    const int b = bh >> 3, h = bh & 7;
    const int wave = threadIdx.x >> 6, lane = threadIdx.x & 63;
    const int c = cg * 4 + wave;
    const size_t tok0 = (size_t)b * LSEQ + c * LC;
    const float A = -expf(alog[h]);
    float dt = dtf[(tok0 + lane) * NH + h];
    float q = dt * A * LOG2E;
    #pragma unroll
    for (int o = 1; o <= 32; o <<= 1) {
        float tmp = __shfl_up(q, o);
        if (lane >= o) q += tmp;
    }
    float qL = __shfl(q, 63);
    wl[wave][lane] = exp2f(qL - q) * dt;
    const unsigned short* xrow = xcb + tok0 * CDIM;
    #pragma unroll
    for (int it = 0; it < 4; it++) {
        int f = it * 64 + lane, r = f >> 2, c8 = (f & 3) * 8;
        *(bf16x8*)&Xl[wave][r * 40 + c8] = *(const bf16x8*)(xrow + (size_t)r * CDIM + h * HD + c8);
    }
    #pragma unroll
    for (int it = 0; it < 8; it++) {
        int f = it * 64 + lane, r = f >> 3, c8 = (f & 7) * 8;
        float w = wl[wave][r];
        bf16x8 v = *(const bf16x8*)(xrow + (size_t)r * CDIM + 256 + c8);
        bf16x8 o;
        #pragma unroll
        for (int j = 0; j < 8; j++) o[j] = (bf16)((float)v[j] * w);
        *(bf16x8*)&Wl[wave][r * 72 + c8] = o;
    }
    const int m = lane & 15, ko = lane >> 4;
    f32x4 hacc[4][2] = {};
    #pragma unroll
    for (int kh = 0; kh < 2; kh++) {
        bf16x8 xb[2];
        #pragma unroll
        for (int pi = 0; pi < 2; pi++)
            #pragma unroll
            for (int j = 0; j < 8; j++)
                xb[pi][j] = Xl[wave][(kh * 32 + ko * 8 + j) * 40 + pi * 16 + m];
        #pragma unroll
        for (int ni = 0; ni < 4; ni++) {
            bf16x8 af;
            #pragma unroll
            for (int j = 0; j < 8; j++)
                af[j] = Wl[wave][(kh * 32 + ko * 8 + j) * 72 + ni * 16 + m];
            #pragma unroll
            for (int pi = 0; pi < 2; pi++)
                hacc[ni][pi] = __builtin_amdgcn_mfma_f32_16x16x32_bf16(af, xb[pi], hacc[ni][pi], 0, 0, 0);
        }
    }
    float* hb = hst + (((size_t)bh * NC + c) << 11);
    #pragma unroll
    for (int ni = 0; ni < 4; ni++)
        #pragma unroll
        for (int pi = 0; pi < 2; pi++)
            #pragma unroll
            for (int r = 0; r < 4; r++)
                hb[(ni * 16 + ko * 4 + r) * 32 + pi * 16 + m] = hacc[ni][pi][r];
    if (lane == 0) dAp[(size_t)bh * NC + c] = exp2f(qL);
}

// ---------------- 5b. SSM pass 2: scan, 2 chains/thread + prefetch -------------
__global__ __launch_bounds__(256) void k_ssm2(float* __restrict__ hst,
                                              const float* __restrict__ dAp) {
    __shared__ float dl[2][NC];
    const int pr = blockIdx.x >> 3, seg = blockIdx.x & 7;
    const int bh0 = pr * 2, bh1 = pr * 2 + 1;
    const int s = seg * 256 + threadIdx.x;
    if (threadIdx.x < NC) dl[0][threadIdx.x] = dAp[(size_t)bh0 * NC + threadIdx.x];
    else if (threadIdx.x < 2 * NC) dl[1][threadIdx.x - NC] = dAp[(size_t)bh1 * NC + threadIdx.x - NC];
    __syncthreads();
    float* b0 = hst + ((size_t)bh0 * NC << 11) + s;
    float* b1 = hst + ((size_t)bh1 * NC << 11) + s;
    float r0 = 0.f, r1 = 0.f;
    float n0 = b0[0], n1 = b1[0];
    for (int c = 0; c < NC; c++) {
        float t0 = n0, t1 = n1;
        if (c + 1 < NC) {
            n0 = b0[(size_t)(c + 1) << 11];
            n1 = b1[(size_t)(c + 1) << 11];
        }
        b0[(size_t)c << 11] = r0;
        b1[(size_t)c << 11] = r1;
        r0 = fmaf(r0, dl[0][c], t0);
        r1 = fmaf(r1, dl[1][c], t1);
    }
}

// ---------------- 5c. SSD pass 3: Y = P.X + diag(2^q).(C.h_in^T), bf16 out -----
__global__ __launch_bounds__(256, 2) void k_ssd3(const unsigned short* __restrict__ xcb,
                                                 const float* __restrict__ dtf,
                                                 const float* __restrict__ alog,
                                                 const float* __restrict__ hst,
                                                 const float* __restrict__ Dw,
                                                 unsigned short* __restrict__ ybb) {
    __shared__ bf16 Pl[4][64 * 72];
    __shared__ bf16 Xl[4][64 * 40];
    __shared__ bf16 Hl[4][64 * 36];
    __shared__ float ql[4][64];
    __shared__ float dl[4][64];
    const int bh = blockIdx.x >> 4, cg = blockIdx.x & 15;
    const int b = bh >> 3, h = bh & 7;
    const int wave = threadIdx.x >> 6, lane = threadIdx.x & 63;
    const int c = cg * 4 + wave;
    const size_t tok0 = (size_t)b * LSEQ + c * LC;
    const float A = -expf(alog[h]);
    const float Dh = Dw[h];
    float dt = dtf[(tok0 + lane) * NH + h];
    float q = dt * A * LOG2E;
    #pragma unroll
    for (int o = 1; o <= 32; o <<= 1) {
        float tmp = __shfl_up(q, o);
        if (lane >= o) q += tmp;
    }
    ql[wave][lane] = q;
    dl[wave][lane] = dt;
    const unsigned short* xrow = xcb + tok0 * CDIM;
    #pragma unroll
    for (int it = 0; it < 4; it++) {
        int f = it * 64 + lane, r = f >> 2, c8 = (f & 3) * 8;
        *(bf16x8*)&Xl[wave][r * 40 + c8] = *(const bf16x8*)(xrow + (size_t)r * CDIM + h * HD + c8);
    }
    const float* hbg = hst + (((size_t)bh * NC + c) << 11);
    #pragma unroll
    for (int it = 0; it < 8; it++) {
        int f = it * 64 + lane, r = f >> 3, c4 = (f & 7) * 4;
        float4 v = *(const float4*)(hbg + r * 32 + c4);
        bf16x4 o; o[0] = (bf16)v.x; o[1] = (bf16)v.y; o[2] = (bf16)v.z; o[3] = (bf16)v.w;
        *(bf16x4*)&Hl[wave][r * 36 + c4] = o;
    }
    const int m = lane & 15, ko = lane >> 4;
    bf16x8 cf[4][2];
    #pragma unroll
    for (int ti = 0; ti < 4; ti++)
        #pragma unroll
        for (int kh = 0; kh < 2; kh++)
            cf[ti][kh] = *(const bf16x8*)(xrow + (size_t)(ti * 16 + m) * CDIM + 320 + kh * 32 + ko * 8);
    f32x4 g[4][4] = {};
    #pragma unroll
    for (int kh = 0; kh < 2; kh++) {
        bf16x8 bfg[4];
        #pragma unroll
        for (int si = 0; si < 4; si++)
            bfg[si] = *(const bf16x8*)(xrow + (size_t)(si * 16 + m) * CDIM + 256 + kh * 32 + ko * 8);
        #pragma unroll
        for (int ti = 0; ti < 4; ti++)
            #pragma unroll
            for (int si = 0; si < 4; si++)
                g[ti][si] = __builtin_amdgcn_mfma_f32_16x16x32_bf16(cf[ti][kh], bfg[si], g[ti][si], 0, 0, 0);
    }
    __syncthreads();
    float qt[4][4], et[4][4];
    #pragma unroll
    for (int ti = 0; ti < 4; ti++)
        #pragma unroll
        for (int r = 0; r < 4; r++) {
            float v = ql[wave][ti * 16 + ko * 4 + r];
            qt[ti][r] = v; et[ti][r] = exp2f(v);
        }
    float qs[4], ds[4];
    #pragma unroll
    for (int si = 0; si < 4; si++) {
        qs[si] = ql[wave][si * 16 + m];
        ds[si] = dl[wave][si * 16 + m];
    }
    #pragma unroll
    for (int ti = 0; ti < 4; ti++)
        #pragma unroll
        for (int si = 0; si < 4; si++)
            #pragma unroll
            for (int r = 0; r < 4; r++) {
                int t = ti * 16 + ko * 4 + r, s = si * 16 + m;
                float p = 0.f;
                if (si <= ti) {
                    float w = (s <= t) ? exp2f(qt[ti][r] - qs[si]) * ds[si] : 0.f;
                    p = g[ti][si][r] * w;
                    if (s == t) p += Dh;
                }
                Pl[wave][t * 72 + s] = (bf16)p;
            }
    f32x4 ya[4][2] = {}, ua[4][2] = {};
    #pragma unroll
    for (int kh = 0; kh < 2; kh++) {
        bf16x8 xb[2], hb2[2];
        #pragma unroll
        for (int pi = 0; pi < 2; pi++)
            #pragma unroll
            for (int j = 0; j < 8; j++) {
                int kk = kh * 32 + ko * 8 + j;
                xb[pi][j]  = Xl[wave][kk * 40 + pi * 16 + m];
                hb2[pi][j] = Hl[wave][kk * 36 + pi * 16 + m];
            }
        #pragma unroll
        for (int ti = 0; ti < 4; ti++) {
            bf16x8 pa = *(const bf16x8*)&Pl[wave][(ti * 16 + m) * 72 + kh * 32 + ko * 8];
            #pragma unroll
            for (int pi = 0; pi < 2; pi++) {
                ya[ti][pi] = __builtin_amdgcn_mfma_f32_16x16x32_bf16(pa, xb[pi], ya[ti][pi], 0, 0, 0);
                ua[ti][pi] = __builtin_amdgcn_mfma_f32_16x16x32_bf16(cf[ti][kh], hb2[pi], ua[ti][pi], 0, 0, 0);
            }
        }
    }
    unsigned short* yrow = ybb + tok0 * DI + h * HD;
    #pragma unroll
    for (int ti = 0; ti < 4; ti++)
        #pragma unroll
        for (int pi = 0; pi < 2; pi++)
            #pragma unroll
            for (int r = 0; r < 4; r++) {
                int t = ti * 16 + ko * 4 + r;
                yrow[(size_t)t * DI + pi * 16 + m] =
                    f2bfbits(ya[ti][pi][r] + et[ti][r] * ua[ti][pi][r]);
            }
}

// ---------------- 6+7. fused gate + GEMM2 + residual ---------------------------
// stage gated row (unnormalized) in As while accumulating row sum-squares,
// rsqrt via LDS reduction, rescale in place, then MFMA (64x128 out per block)
__global__ __launch_bounds__(256) void k_gemm2g(const unsigned short* __restrict__ ybb,
                                                const unsigned short* __restrict__ zb,
                                                const float* __restrict__ gw,
                                                const unsigned short* __restrict__ w2b,
                                                const float* __restrict__ xin,
                                                float* __restrict__ out) {
    __shared__ bf16 As[64 * 264];
    __shared__ bf16 Bs[128 * 72];
    __shared__ float gwl[256];
    __shared__ float ssb[64][4];
    __shared__ float rsb[64];
    const int t = threadIdx.x;
    const int m0 = blockIdx.x * 64;
    gwl[t] = gw[t];
    const int r = t >> 2, q = (t & 3) * 64;
    const unsigned short* yrow = ybb + (size_t)(m0 + r) * DI + q;
    const unsigned short* zrow = zb + (size_t)(m0 + r) * DI + q;
    float ss = 0.f;
    #pragma unroll
    for (int i = 0; i < 8; i++) {
        bf16x8 yv = *(const bf16x8*)(yrow + i * 8);
        bf16x8 zv = *(const bf16x8*)(zrow + i * 8);
        bf16x8 g8;
        #pragma unroll
        for (int j = 0; j < 8; j++) {
            float z = (float)zv[j];
            float g = (float)yv[j] * (z / (1.f + expf(-z)));
            ss += g * g;
            g8[j] = (bf16)g;
        }
        *(bf16x8*)&As[r * 264 + q + i * 8] = g8;
    }
    ssb[r][t & 3] = ss;
    __syncthreads();
    if (t < 64) {
        float s = ssb[t][0] + ssb[t][1] + ssb[t][2] + ssb[t][3];
        rsb[t] = rsqrtf(s * (1.0f / DI) + EPSF);
    }
    __syncthreads();
    const float rs = rsb[r];
    #pragma unroll
    for (int i = 0; i < 8; i++) {
        bf16x8 g8 = *(const bf16x8*)&As[r * 264 + q + i * 8];
        #pragma unroll
        for (int j = 0; j < 8; j++)
            g8[j] = (bf16)((float)g8[j] * rs * gwl[q + i * 8 + j]);
        *(bf16x8*)&As[r * 264 + q + i * 8] = g8;
    }
    const int wave = t >> 6, lane = t & 63;
    const int wm = wave >> 1, wn = wave & 1;
    const int fr = lane & 15, fk = (lane >> 4) * 8;
    f32x4 acc[2][4] = {};
    for (int k0 = 0; k0 < DI; k0 += 64) {
        __syncthreads();
        #pragma unroll
        for (int i = 0; i < 4; i++) {
            int f = i * 256 + t, row = f >> 3, c8 = (f & 7) * 8;
            *(short8*)&Bs[row * 72 + c8] = *(const short8*)((const unsigned short*)w2b + (size_t)row * DI + k0 + c8);
        }
        __syncthreads();
        #pragma unroll
        for (int kk = 0; kk < 64; kk += 32) {
            #pragma unroll
            for (int mt = 0; mt < 2; mt++) {
                bf16x8 af = *(const bf16x8*)&As[(wm * 32 + mt * 16 + fr) * 264 + k0 + kk + fk];
                #pragma unroll
                for (int nt = 0; nt < 4; nt++) {
                    bf16x8 bf = *(const bf16x8*)&Bs[(wn * 64 + nt * 16 + fr) * 72 + kk + fk];
                    acc[mt][nt] = __builtin_amdgcn_mfma_f32_16x16x32_bf16(af, bf, acc[mt][nt], 0, 0, 0);
                }
            }
        }
    }
    #pragma unroll
    for (int mt = 0; mt < 2; mt++)
        #pragma unroll
        for (int nt = 0; nt < 4; nt++) {
            int n = wn * 64 + nt * 16 + fr;
            #pragma unroll
            for (int rr = 0; rr < 4; rr++) {
                int m = m0 + wm * 32 + mt * 16 + (lane >> 4) * 4 + rr;
                out[(size_t)m * DM + n] = xin[(size_t)m * DM + n] + acc[mt][nt][rr];
            }
        }
}

extern "C" void kernel_launch(void* const* d_in, const int* in_sizes, int n_in,
                              void* d_out, int out_size, void* d_ws, size_t ws_size,
                              hipStream_t stream) {
    const float* x   = (const float*)d_in[0];
    const float* nw  = (const float*)d_in[1];
    const float* w1  = (const float*)d_in[2];
    const float* cw  = (const float*)d_in[3];
    const float* cb  = (const float*)d_in[4];
    const float* dtb = (const float*)d_in[5];
    const float* al  = (const float*)d_in[6];
    const float* Dw  = (const float*)d_in[7];
    const float* gw  = (const float*)d_in[8];
    const float* w2  = (const float*)d_in[9];
    float* out = (float*)d_out;

    float* ws = (float*)d_ws;
    float*  hst = ws;                                   // 64*64*2048 fp32
    float*  dAp = hst + (size_t)NB * NH * NC * 2048;    // 4096
    float*  dtf = dAp + NB * NH * NC;                   // NTOK*8 fp32
    unsigned short* zb  = (unsigned short*)(dtf + (size_t)NTOK * NH);  // NTOK*256 bf16
    unsigned short* xbc = zb + (size_t)NTOK * DI;                      // NTOK*384 bf16
    unsigned short* xcb = xbc + (size_t)NTOK * CDIM;                   // NTOK*384 bf16
    unsigned short* ybb = xcb + (size_t)NTOK * CDIM;                   // NTOK*256 bf16
    unsigned short* w1b = ybb + (size_t)NTOK * DI;                     // 648*128
    unsigned short* w2b = w1b + (size_t)DPROJ * DM;                    // 128*256
    // aliases (lifetimes disjoint):
    float*          xnf = hst;                  // dead before ssd1 writes hst
    unsigned short* xnb = ybb;                  // dead before ssd3 writes ybb

    k_cast<<<(DPROJ * DM + 255) / 256, 256, 0, stream>>>(w1, w1b, DPROJ * DM);
    k_cast<<<(DM * DI + 255) / 256, 256, 0, stream>>>(w2, w2b, DM * DI);
    k_rmsnorm<<<NTOK / 4, 256, 0, stream>>>(x, nw, xnf, xnb);
    k_gemm1<<<dim3(NTOK / 64, (DPROJ + 63) / 64), 256, 0, stream>>>(xnb, w1b, zb, xbc);
    k_conv<<<NTOK / 64, 384, 0, stream>>>(xbc, cw, cb, xcb);
    k_dt<<<NTOK / 32, 256, 0, stream>>>(xnf, w1, dtb, dtf);
    k_ssd1<<<NB * NH * (NC / 4), 256, 0, stream>>>(xcb, dtf, al, hst, dAp);
    k_ssm2<<<(NB * NH / 2) * 8, 256, 0, stream>>>(hst, dAp);
    k_ssd3<<<NB * NH * (NC / 4), 256, 0, stream>>>(xcb, dtf, al, hst, Dw, ybb);
    k_gemm2g<<<NTOK / 64, 256, 0, stream>>>(ybb, zb, gw, w2b, x, out);
}

// Round 9
// 195.633 us; speedup vs baseline: 17.2459x; 1.0312x over previous
//
#include <hip/hip_runtime.h>

#define DM    128
#define DI    256
#define NH    8
#define HD    32
#define NS    64
#define CDIM  384
#define DPROJ 648
#define LSEQ  4096
#define NB    8
#define NTOK  32768          // NB*LSEQ
#define LC    64             // chunk length
#define NC    64             // chunks per (b,h) sequence
#define EPSF  1e-5f
#define LOG2E 1.4426950408889634f

typedef __bf16 bf16;
typedef bf16  bf16x8 __attribute__((ext_vector_type(8)));
typedef bf16  bf16x4 __attribute__((ext_vector_type(4)));
typedef short short8 __attribute__((ext_vector_type(8)));
typedef float f32x4  __attribute__((ext_vector_type(4)));

__device__ __forceinline__ unsigned short f2bfbits(float f) {
    unsigned int u = __float_as_uint(f);
    unsigned int r = u + 0x7FFFu + ((u >> 16) & 1u);   // RNE
    return (unsigned short)(r >> 16);
}
__device__ __forceinline__ float bfbits2f(unsigned short u) {
    return __uint_as_float(((unsigned int)u) << 16);
}

// ---------------- 0. fp32 -> bf16 weight cast ----------------------------------
__global__ __launch_bounds__(256) void k_cast(const float* __restrict__ in,
                                              unsigned short* __restrict__ out, int n) {
    int i = blockIdx.x * 256 + threadIdx.x;
    if (i < n) out[i] = f2bfbits(in[i]);
}

// ---------------- 1. fused input RMSNorm + dt ----------------------------------
// block = 4 tokens (wave each). xn -> bf16 out + LDS; dt = softplus(xn.W1d+b)
// via 8-lane sub-reduction (3 shuffles), fp32 end-to-end for the exp path.
__global__ __launch_bounds__(256) void k_rmsdt(const float* __restrict__ x,
                                               const float* __restrict__ w,
                                               const float* __restrict__ w1,
                                               const float* __restrict__ dtb,
                                               unsigned short* __restrict__ xnb,
                                               float* __restrict__ dtf) {
    __shared__ float Xs[4][132];
    __shared__ float Wd[8][132];
    const int t = threadIdx.x;
    {
        int row = t >> 5, col = (t & 31) * 4;           // 8x128 = 256 float4
        *(float4*)&Wd[row][col] = *(const float4*)(w1 + (size_t)(640 + row) * DM + col);
    }
    const int wave = t >> 6, lane = t & 63;
    const size_t row = (size_t)blockIdx.x * 4 + wave;
    const float* xr = x + row * DM + lane * 2;
    float v0 = xr[0], v1 = xr[1];
    float ss = v0 * v0 + v1 * v1;
    #pragma unroll
    for (int o = 32; o; o >>= 1) ss += __shfl_xor(ss, o);
    float r = rsqrtf(ss * (1.0f / DM) + EPSF);
    float o0 = v0 * r * w[lane * 2], o1 = v1 * r * w[lane * 2 + 1];
    Xs[wave][lane * 2] = o0; Xs[wave][lane * 2 + 1] = o1;
    ushort2 ob; ob.x = f2bfbits(o0); ob.y = f2bfbits(o1);
    *(ushort2*)(xnb + row * DM + lane * 2) = ob;
    __syncthreads();
    const int h = lane >> 3, ks = lane & 7;
    float acc = 0.f;
    #pragma unroll
    for (int i = 0; i < 4; i++) {
        float4 xv = *(const float4*)&Xs[wave][ks * 16 + i * 4];
        float4 wv = *(const float4*)&Wd[h][ks * 16 + i * 4];
        acc = fmaf(xv.x, wv.x, acc);
        acc = fmaf(xv.y, wv.y, acc);
        acc = fmaf(xv.z, wv.z, acc);
        acc = fmaf(xv.w, wv.w, acc);
    }
    acc += __shfl_xor(acc, 1);
    acc += __shfl_xor(acc, 2);
    acc += __shfl_xor(acc, 4);
    if (ks == 0) {
        float v = acc + dtb[h];
        dtf[row * NH + h] = (v > 20.f) ? v : log1pf(expf(v));
    }
}

// ---------------- 2. GEMM1 (bf16 MFMA): split bf16 out (z | xBC) ---------------
__global__ __launch_bounds__(256) void k_gemm1(const unsigned short* __restrict__ A,
                                               const unsigned short* __restrict__ B,
                                               unsigned short* __restrict__ zb,
                                               unsigned short* __restrict__ xbc) {
    __shared__ bf16 As[64 * 40];
    __shared__ bf16 Bs[64 * 40];
    const int t = threadIdx.x;
    const int m0 = blockIdx.x * 64, n0 = blockIdx.y * 64;
    const int wave = t >> 6, lane = t & 63;
    const int wm = wave >> 1, wn = wave & 1;
    const int fr = lane & 15, fk = (lane >> 4) * 8;
    f32x4 acc[2][2] = {};
    const int r = t >> 2, q = (t & 3) * 8;
    for (int k0 = 0; k0 < DM; k0 += 32) {
        __syncthreads();
        *(short8*)&As[r * 40 + q] = *(const short8*)(A + (size_t)(m0 + r) * DM + k0 + q);
        short8 bv = {};
        if (n0 + r < DPROJ) bv = *(const short8*)(B + (size_t)(n0 + r) * DM + k0 + q);
        *(short8*)&Bs[r * 40 + q] = bv;
        __syncthreads();
        #pragma unroll
        for (int mt = 0; mt < 2; mt++) {
            bf16x8 af = *(const bf16x8*)&As[(wm * 32 + mt * 16 + fr) * 40 + fk];
            #pragma unroll
            for (int nt = 0; nt < 2; nt++) {
                bf16x8 bf = *(const bf16x8*)&Bs[(wn * 32 + nt * 16 + fr) * 40 + fk];
                acc[mt][nt] = __builtin_amdgcn_mfma_f32_16x16x32_bf16(af, bf, acc[mt][nt], 0, 0, 0);
            }
        }
    }
    #pragma unroll
    for (int mt = 0; mt < 2; mt++)
        #pragma unroll
        for (int nt = 0; nt < 2; nt++) {
            int n = n0 + wn * 32 + nt * 16 + fr;
            if (n >= 640) continue;
            #pragma unroll
            for (int rr = 0; rr < 4; rr++) {
                int m = m0 + wm * 32 + mt * 16 + (lane >> 4) * 4 + rr;
                unsigned short v = f2bfbits(acc[mt][nt][rr]);
                if (n < DI) zb[(size_t)m * DI + n] = v;
                else        xbc[(size_t)m * CDIM + (n - 256)] = v;
            }
        }
}

// ---------------- 3. causal depthwise conv (K=4) + SiLU, bf16 ------------------
__global__ __launch_bounds__(384) void k_conv(const unsigned short* __restrict__ xbc,
                                              const float* __restrict__ cw,
                                              const float* __restrict__ cb,
                                              unsigned short* __restrict__ xcb) {
    const int c = threadIdx.x;
    const int t0 = blockIdx.x * 64;
    const int l0 = t0 & (LSEQ - 1);
    float4 wv = *(const float4*)(cw + c * 4);
    float bias = cb[c];
    const unsigned short* in = xbc + (size_t)t0 * CDIM + c;
    unsigned short* out = xcb + (size_t)t0 * CDIM + c;
    float h1 = 0.f, h2 = 0.f, h3 = 0.f;
    if (l0) {
        h1 = bfbits2f(in[-CDIM]);
        h2 = bfbits2f(in[-2 * CDIM]);
        h3 = bfbits2f(in[-3 * CDIM]);
    }
    #pragma unroll 4
    for (int t = 0; t < 64; t++) {
        float x0 = bfbits2f(in[(size_t)t * CDIM]);
        float acc = bias;
        acc = fmaf(x0, wv.w, acc);
        acc = fmaf(h1, wv.z, acc);
        acc = fmaf(h2, wv.y, acc);
        acc = fmaf(h3, wv.x, acc);
        float s = acc / (1.f + expf(-acc));
        out[(size_t)t * CDIM] = f2bfbits(s);
        h3 = h2; h2 = h1; h1 = x0;
    }
}

// ---------------- 5a. SSD pass 1: chunk-local end state via MFMA, bf16 hst -----
__global__ __launch_bounds__(256, 2) void k_ssd1(const unsigned short* __restrict__ xcb,
                                                 const float* __restrict__ dtf,
                                                 const float* __restrict__ alog,
                                                 unsigned short* __restrict__ hst,
                                                 float* __restrict__ dAp) {
    __shared__ bf16 Wl[4][64 * 72];
    __shared__ bf16 Xl[4][64 * 40];
    __shared__ float wl[4][64];
    const int bh = blockIdx.x >> 4, cg = blockIdx.x & 15;
    const int b = bh >> 3, h = bh & 7;
    const int wave = threadIdx.x >> 6, lane = threadIdx.x & 63;
    const int c = cg * 4 + wave;
    const size_t tok0 = (size_t)b * LSEQ + c * LC;
    const float A = -expf(alog[h]);
    float dt = dtf[(tok0 + lane) * NH + h];
    float q = dt * A * LOG2E;
    #pragma unroll
    for (int o = 1; o <= 32; o <<= 1) {
        float tmp = __shfl_up(q, o);
        if (lane >= o) q += tmp;
    }
    float qL = __shfl(q, 63);
    wl[wave][lane] = exp2f(qL - q) * dt;
    const unsigned short* xrow = xcb + tok0 * CDIM;
    #pragma unroll
    for (int it = 0; it < 4; it++) {
        int f = it * 64 + lane, r = f >> 2, c8 = (f & 3) * 8;
        *(bf16x8*)&Xl[wave][r * 40 + c8] = *(const bf16x8*)(xrow + (size_t)r * CDIM + h * HD + c8);
    }
    #pragma unroll
    for (int it = 0; it < 8; it++) {
        int f = it * 64 + lane, r = f >> 3, c8 = (f & 7) * 8;
        float w = wl[wave][r];
        bf16x8 v = *(const bf16x8*)(xrow + (size_t)r * CDIM + 256 + c8);
        bf16x8 o;
        #pragma unroll
        for (int j = 0; j < 8; j++) o[j] = (bf16)((float)v[j] * w);
        *(bf16x8*)&Wl[wave][r * 72 + c8] = o;
    }
    const int m = lane & 15, ko = lane >> 4;
    f32x4 hacc[4][2] = {};
    #pragma unroll
    for (int kh = 0; kh < 2; kh++) {
        bf16x8 xb[2];
        #pragma unroll
        for (int pi = 0; pi < 2; pi++)
            #pragma unroll
            for (int j = 0; j < 8; j++)
                xb[pi][j] = Xl[wave][(kh * 32 + ko * 8 + j) * 40 + pi * 16 + m];
        #pragma unroll
        for (int ni = 0; ni < 4; ni++) {
            bf16x8 af;
            #pragma unroll
            for (int j = 0; j < 8; j++)
                af[j] = Wl[wave][(kh * 32 + ko * 8 + j) * 72 + ni * 16 + m];
            #pragma unroll
            for (int pi = 0; pi < 2; pi++)
                hacc[ni][pi] = __builtin_amdgcn_mfma_f32_16x16x32_bf16(af, xb[pi], hacc[ni][pi], 0, 0, 0);
        }
    }
    unsigned short* hb = hst + (((size_t)bh * NC + c) << 11);
    #pragma unroll
    for (int ni = 0; ni < 4; ni++)
        #pragma unroll
        for (int pi = 0; pi < 2; pi++)
            #pragma unroll
            for (int r = 0; r < 4; r++)
                hb[(ni * 16 + ko * 4 + r) * 32 + pi * 16 + m] = f2bfbits(hacc[ni][pi][r]);
    if (lane == 0) dAp[(size_t)bh * NC + c] = exp2f(qL);
}

// ---------------- 5b. SSM pass 2: scan over bf16 chunk states ------------------
__global__ __launch_bounds__(256) void k_ssm2(unsigned short* __restrict__ hst,
                                              const float* __restrict__ dAp) {
    __shared__ float dl[2][NC];
    const int pr = blockIdx.x >> 3, seg = blockIdx.x & 7;
    const int bh0 = pr * 2, bh1 = pr * 2 + 1;
    const int s = seg * 256 + threadIdx.x;
    if (threadIdx.x < NC) dl[0][threadIdx.x] = dAp[(size_t)bh0 * NC + threadIdx.x];
    else if (threadIdx.x < 2 * NC) dl[1][threadIdx.x - NC] = dAp[(size_t)bh1 * NC + threadIdx.x - NC];
    __syncthreads();
    unsigned short* b0 = hst + ((size_t)bh0 * NC << 11) + s;
    unsigned short* b1 = hst + ((size_t)bh1 * NC << 11) + s;
    float r0 = 0.f, r1 = 0.f;
    float n0 = bfbits2f(b0[0]), n1 = bfbits2f(b1[0]);
    for (int c = 0; c < NC; c++) {
        float t0 = n0, t1 = n1;
        if (c + 1 < NC) {
            n0 = bfbits2f(b0[(size_t)(c + 1) << 11]);
            n1 = bfbits2f(b1[(size_t)(c + 1) << 11]);
        }
        b0[(size_t)c << 11] = f2bfbits(r0);
        b1[(size_t)c << 11] = f2bfbits(r1);
        r0 = fmaf(r0, dl[0][c], t0);
        r1 = fmaf(r1, dl[1][c], t1);
    }
}

// ---------------- 5c. SSD pass 3: Y = P.X + diag(2^q).(C.h_in^T), bf16 out -----
__global__ __launch_bounds__(256, 2) void k_ssd3(const unsigned short* __restrict__ xcb,
                                                 const float* __restrict__ dtf,
                                                 const float* __restrict__ alog,
                                                 const unsigned short* __restrict__ hst,
                                                 const float* __restrict__ Dw,
                                                 unsigned short* __restrict__ ybb) {
    __shared__ bf16 Pl[4][64 * 72];
    __shared__ bf16 Xl[4][64 * 40];
    __shared__ bf16 Hl[4][64 * 40];
    __shared__ float ql[4][64];
    __shared__ float dl[4][64];
    const int bh = blockIdx.x >> 4, cg = blockIdx.x & 15;
    const int b = bh >> 3, h = bh & 7;
    const int wave = threadIdx.x >> 6, lane = threadIdx.x & 63;
    const int c = cg * 4 + wave;
    const size_t tok0 = (size_t)b * LSEQ + c * LC;
    const float A = -expf(alog[h]);
    const float Dh = Dw[h];
    float dt = dtf[(tok0 + lane) * NH + h];
    float q = dt * A * LOG2E;
    #pragma unroll
    for (int o = 1; o <= 32; o <<= 1) {
        float tmp = __shfl_up(q, o);
        if (lane >= o) q += tmp;
    }
    ql[wave][lane] = q;
    dl[wave][lane] = dt;
    const unsigned short* xrow = xcb + tok0 * CDIM;
    #pragma unroll
    for (int it = 0; it < 4; it++) {
        int f = it * 64 + lane, r = f >> 2, c8 = (f & 3) * 8;
        *(bf16x8*)&Xl[wave][r * 40 + c8] = *(const bf16x8*)(xrow + (size_t)r * CDIM + h * HD + c8);
    }
    const unsigned short* hbg = hst + (((size_t)bh * NC + c) << 11);
    #pragma unroll
    for (int it = 0; it < 4; it++) {
        int f = it * 64 + lane, n = f >> 2, p8 = (f & 3) * 8;
        *(bf16x8*)&Hl[wave][n * 40 + p8] = *(const bf16x8*)(hbg + f * 8);
    }
    const int m = lane & 15, ko = lane >> 4;
    bf16x8 cf[4][2];
    #pragma unroll
    for (int ti = 0; ti < 4; ti++)
        #pragma unroll
        for (int kh = 0; kh < 2; kh++)
            cf[ti][kh] = *(const bf16x8*)(xrow + (size_t)(ti * 16 + m) * CDIM + 320 + kh * 32 + ko * 8);
    f32x4 g[4][4] = {};
    #pragma unroll
    for (int kh = 0; kh < 2; kh++) {
        bf16x8 bfg[4];
        #pragma unroll
        for (int si = 0; si < 4; si++)
            bfg[si] = *(const bf16x8*)(xrow + (size_t)(si * 16 + m) * CDIM + 256 + kh * 32 + ko * 8);
        #pragma unroll
        for (int ti = 0; ti < 4; ti++)
            #pragma unroll
            for (int si = 0; si < 4; si++)
                g[ti][si] = __builtin_amdgcn_mfma_f32_16x16x32_bf16(cf[ti][kh], bfg[si], g[ti][si], 0, 0, 0);
    }
    __syncthreads();
    float qt[4][4], et[4][4];
    #pragma unroll
    for (int ti = 0; ti < 4; ti++)
        #pragma unroll
        for (int r = 0; r < 4; r++) {
            float v = ql[wave][ti * 16 + ko * 4 + r];
            qt[ti][r] = v; et[ti][r] = exp2f(v);
        }
    float qs[4], ds[4];
    #pragma unroll
    for (int si = 0; si < 4; si++) {
        qs[si] = ql[wave][si * 16 + m];
        ds[si] = dl[wave][si * 16 + m];
    }
    #pragma unroll
    for (int ti = 0; ti < 4; ti++)
        #pragma unroll
        for (int si = 0; si < 4; si++)
            #pragma unroll
            for (int r = 0; r < 4; r++) {
                int t = ti * 16 + ko * 4 + r, s = si * 16 + m;
                float p = 0.f;
                if (si <= ti) {
                    float w = (s <= t) ? exp2f(qt[ti][r] - qs[si]) * ds[si] : 0.f;
                    p = g[ti][si][r] * w;
                    if (s == t) p += Dh;
                }
                Pl[wave][t * 72 + s] = (bf16)p;
            }
    f32x4 ya[4][2] = {}, ua[4][2] = {};
    #pragma unroll
    for (int kh = 0; kh < 2; kh++) {
        bf16x8 xb[2], hb2[2];
        #pragma unroll
        for (int pi = 0; pi < 2; pi++)
            #pragma unroll
            for (int j = 0; j < 8; j++) {
                int kk = kh * 32 + ko * 8 + j;
                xb[pi][j]  = Xl[wave][kk * 40 + pi * 16 + m];
                hb2[pi][j] = Hl[wave][kk * 40 + pi * 16 + m];
            }
        #pragma unroll
        for (int ti = 0; ti < 4; ti++) {
            bf16x8 pa = *(const bf16x8*)&Pl[wave][(ti * 16 + m) * 72 + kh * 32 + ko * 8];
            #pragma unroll
            for (int pi = 0; pi < 2; pi++) {
                ya[ti][pi] = __builtin_amdgcn_mfma_f32_16x16x32_bf16(pa, xb[pi], ya[ti][pi], 0, 0, 0);
                ua[ti][pi] = __builtin_amdgcn_mfma_f32_16x16x32_bf16(cf[ti][kh], hb2[pi], ua[ti][pi], 0, 0, 0);
            }
        }
    }
    unsigned short* yrow = ybb + tok0 * DI + h * HD;
    #pragma unroll
    for (int ti = 0; ti < 4; ti++)
        #pragma unroll
        for (int pi = 0; pi < 2; pi++)
            #pragma unroll
            for (int r = 0; r < 4; r++) {
                int t = ti * 16 + ko * 4 + r;
                yrow[(size_t)t * DI + pi * 16 + m] =
                    f2bfbits(ya[ti][pi][r] + et[ti][r] * ua[ti][pi][r]);
            }
}

// ---------------- 6+7. fused gate + GEMM2 + residual ---------------------------
__global__ __launch_bounds__(256) void k_gemm2g(const unsigned short* __restrict__ ybb,
                                                const unsigned short* __restrict__ zb,
                                                const float* __restrict__ gw,
                                                const unsigned short* __restrict__ w2b,
                                                const float* __restrict__ xin,
                                                float* __restrict__ out) {
    __shared__ bf16 As[64 * 264];
    __shared__ bf16 Bs[128 * 72];
    __shared__ float gwl[256];
    __shared__ float ssb[64][4];
    __shared__ float rsb[64];
    const int t = threadIdx.x;
    const int m0 = blockIdx.x * 64;
    gwl[t] = gw[t];
    const int r = t >> 2, q = (t & 3) * 64;
    const unsigned short* yrow = ybb + (size_t)(m0 + r) * DI + q;
    const unsigned short* zrow = zb + (size_t)(m0 + r) * DI + q;
    float ss = 0.f;
    #pragma unroll
    for (int i = 0; i < 8; i++) {
        bf16x8 yv = *(const bf16x8*)(yrow + i * 8);
        bf16x8 zv = *(const bf16x8*)(zrow + i * 8);
        bf16x8 g8;
        #pragma unroll
        for (int j = 0; j < 8; j++) {
            float z = (float)zv[j];
            float g = (float)yv[j] * (z / (1.f + expf(-z)));
            ss += g * g;
            g8[j] = (bf16)g;
        }
        *(bf16x8*)&As[r * 264 + q + i * 8] = g8;
    }
    ssb[r][t & 3] = ss;
    __syncthreads();
    if (t < 64) {
        float s = ssb[t][0] + ssb[t][1] + ssb[t][2] + ssb[t][3];
        rsb[t] = rsqrtf(s * (1.0f / DI) + EPSF);
    }
    __syncthreads();
    const float rs = rsb[r];
    #pragma unroll
    for (int i = 0; i < 8; i++) {
        bf16x8 g8 = *(const bf16x8*)&As[r * 264 + q + i * 8];
        #pragma unroll
        for (int j = 0; j < 8; j++)
            g8[j] = (bf16)((float)g8[j] * rs * gwl[q + i * 8 + j]);
        *(bf16x8*)&As[r * 264 + q + i * 8] = g8;
    }
    const int wave = t >> 6, lane = t & 63;
    const int wm = wave >> 1, wn = wave & 1;
    const int fr = lane & 15, fk = (lane >> 4) * 8;
    f32x4 acc[2][4] = {};
    for (int k0 = 0; k0 < DI; k0 += 64) {
        __syncthreads();
        #pragma unroll
        for (int i = 0; i < 4; i++) {
            int f = i * 256 + t, row = f >> 3, c8 = (f & 7) * 8;
            *(short8*)&Bs[row * 72 + c8] = *(const short8*)((const unsigned short*)w2b + (size_t)row * DI + k0 + c8);
        }
        __syncthreads();
        #pragma unroll
        for (int kk = 0; kk < 64; kk += 32) {
            #pragma unroll
            for (int mt = 0; mt < 2; mt++) {
                bf16x8 af = *(const bf16x8*)&As[(wm * 32 + mt * 16 + fr) * 264 + k0 + kk + fk];
                #pragma unroll
                for (int nt = 0; nt < 4; nt++) {
                    bf16x8 bf = *(const bf16x8*)&Bs[(wn * 64 + nt * 16 + fr) * 72 + kk + fk];
                    acc[mt][nt] = __builtin_amdgcn_mfma_f32_16x16x32_bf16(af, bf, acc[mt][nt], 0, 0, 0);
                }
            }
        }
    }
    #pragma unroll
    for (int mt = 0; mt < 2; mt++)
        #pragma unroll
        for (int nt = 0; nt < 4; nt++) {
            int n = wn * 64 + nt * 16 + fr;
            #pragma unroll
            for (int rr = 0; rr < 4; rr++) {
                int m = m0 + wm * 32 + mt * 16 + (lane >> 4) * 4 + rr;
                out[(size_t)m * DM + n] = xin[(size_t)m * DM + n] + acc[mt][nt][rr];
            }
        }
}

extern "C" void kernel_launch(void* const* d_in, const int* in_sizes, int n_in,
                              void* d_out, int out_size, void* d_ws, size_t ws_size,
                              hipStream_t stream) {
    const float* x   = (const float*)d_in[0];
    const float* nw  = (const float*)d_in[1];
    const float* w1  = (const float*)d_in[2];
    const float* cw  = (const float*)d_in[3];
    const float* cb  = (const float*)d_in[4];
    const float* dtb = (const float*)d_in[5];
    const float* al  = (const float*)d_in[6];
    const float* Dw  = (const float*)d_in[7];
    const float* gw  = (const float*)d_in[8];
    const float* w2  = (const float*)d_in[9];
    float* out = (float*)d_out;

    float* ws = (float*)d_ws;
    float*  dAp = ws;                                   // 4096 fp32
    float*  dtf = dAp + NB * NH * NC;                   // NTOK*8 fp32
    unsigned short* hst = (unsigned short*)(dtf + (size_t)NTOK * NH); // 64*64*2048 bf16
    unsigned short* zb  = hst + (size_t)NB * NH * NC * 2048;          // NTOK*256 bf16
    unsigned short* xbc = zb + (size_t)NTOK * DI;                     // NTOK*384 bf16
    unsigned short* xcb = xbc + (size_t)NTOK * CDIM;                  // NTOK*384 bf16
    unsigned short* ybb = xcb + (size_t)NTOK * CDIM;                  // NTOK*256 bf16
    unsigned short* w1b = ybb + (size_t)NTOK * DI;                    // 648*128
    unsigned short* w2b = w1b + (size_t)DPROJ * DM;                   // 128*256
    // alias (lifetimes disjoint): xnb dead before ssd3 writes ybb
    unsigned short* xnb = ybb;

    k_cast<<<(DPROJ * DM + 255) / 256, 256, 0, stream>>>(w1, w1b, DPROJ * DM);
    k_cast<<<(DM * DI + 255) / 256, 256, 0, stream>>>(w2, w2b, DM * DI);
    k_rmsdt<<<NTOK / 4, 256, 0, stream>>>(x, nw, w1, dtb, xnb, dtf);
    k_gemm1<<<dim3(NTOK / 64, (DPROJ + 63) / 64), 256, 0, stream>>>(xnb, w1b, zb, xbc);
    k_conv<<<NTOK / 64, 384, 0, stream>>>(xbc, cw, cb, xcb);
    k_ssd1<<<NB * NH * (NC / 4), 256, 0, stream>>>(xcb, dtf, al, hst, dAp);
    k_ssm2<<<(NB * NH / 2) * 8, 256, 0, stream>>>(hst, dAp);
    k_ssd3<<<NB * NH * (NC / 4), 256, 0, stream>>>(xcb, dtf, al, hst, Dw, ybb);
    k_gemm2g<<<NTOK / 64, 256, 0, stream>>>(ybb, zb, gw, w2b, x, out);
}